// Round 1
// baseline (1767.701 us; speedup 1.0000x reference)
//
#include <hip/hip_runtime.h>
#include <math.h>

#define N_NODES 50000
#define N_EDGES 800000
#define DIN 64
#define HC 256      // H*C
#define NH 4        // heads
#define CPH 64      // channels per head
#define ED 11
#define RPB 16      // rows per block in node_proj

__device__ __forceinline__ void atomicMaxF(float* addr, float val) {
    int* ia = (int*)addr;
    int old = __float_as_int(*addr);
    while (__int_as_float(old) < val) {
        int assumed = old;
        old = atomicCAS(ia, assumed, __float_as_int(val));
        if (old == assumed) break;
    }
}

// ---------------------------------------------------------------------------
// K1: Q,K,V node projections. 16 nodes per 256-thread block; thread t owns
// output column t; weight element loaded once per 16 nodes.
__global__ void node_proj(const float* __restrict__ x,
                          const float* __restrict__ Wq,
                          const float* __restrict__ Wk,
                          const float* __restrict__ Wv,
                          float* __restrict__ Q,
                          float* __restrict__ K,
                          float* __restrict__ V) {
    __shared__ float xs[RPB * DIN];
    const int n0 = blockIdx.x * RPB;
    const int t = threadIdx.x;
    // 16 rows x 64 = 1024 floats, 4 contiguous per thread (coalesced)
    #pragma unroll
    for (int i = 0; i < 4; ++i) xs[t * 4 + i] = x[n0 * DIN + t * 4 + i];
    __syncthreads();

    float qa[RPB], ka[RPB], va[RPB];
    #pragma unroll
    for (int r = 0; r < RPB; ++r) { qa[r] = 0.f; ka[r] = 0.f; va[r] = 0.f; }

    for (int d = 0; d < DIN; ++d) {
        const float wq = Wq[d * HC + t];
        const float wk = Wk[d * HC + t];
        const float wv = Wv[d * HC + t];
        #pragma unroll
        for (int r = 0; r < RPB; ++r) {
            const float xv = xs[r * DIN + d];
            qa[r] += xv * wq;
            ka[r] += xv * wk;
            va[r] += xv * wv;
        }
    }
    #pragma unroll
    for (int r = 0; r < RPB; ++r) {
        Q[(n0 + r) * HC + t] = qa[r];
        K[(n0 + r) * HC + t] = ka[r];
        V[(n0 + r) * HC + t] = va[r];
    }
}

// ---------------------------------------------------------------------------
// K0: initialize accumulators in workspace each call (ws is not re-poisoned,
// but we must not rely on leftover state either way).
__global__ void init_ws(float* __restrict__ AMAX, float* __restrict__ DENOM,
                        float* __restrict__ OUT) {
    const int i = blockIdx.x * blockDim.x + threadIdx.x;
    if (i < N_NODES * NH) { AMAX[i] = -INFINITY; DENOM[i] = 0.f; }
    if (i < N_NODES * HC) OUT[i] = 0.f;
}

// ---------------------------------------------------------------------------
// K2: per-edge alpha + segment max. Block = 256 threads = 4 waves; wave h
// computes head h's 64-wide dot via shuffle reduce. e-projection recomputed
// on the fly (11 MACs/thread) to avoid an 819MB [E,256] buffer.
__global__ void edge_alpha(const float* __restrict__ ea,
                           const int* __restrict__ src,
                           const int* __restrict__ dst,
                           const float* __restrict__ We,
                           const float* __restrict__ Q,
                           const float* __restrict__ K,
                           float* __restrict__ ALPHA,
                           float* __restrict__ AMAX) {
    const int e = blockIdx.x;
    const int t = threadIdx.x;
    const int s = src[e], d = dst[e];

    float ev = 0.f;
    #pragma unroll
    for (int j = 0; j < ED; ++j) ev += ea[e * ED + j] * We[j * HC + t];

    const float kv = K[s * HC + t] + ev;
    const float qv = Q[d * HC + t];
    float p = qv * kv;
    #pragma unroll
    for (int off = 32; off > 0; off >>= 1) p += __shfl_xor(p, off, 64);

    if ((t & 63) == 0) {
        const int h = t >> 6;
        const float alpha = p * 0.125f;  // 1/sqrt(64)
        ALPHA[e * NH + h] = alpha;
        atomicMaxF(&AMAX[d * NH + h], alpha);
    }
}

// ---------------------------------------------------------------------------
// K3: unnormalized aggregation: OUT[dst] += ex*(v[src]+e), DENOM[dst] += ex.
__global__ void edge_aggr(const float* __restrict__ ea,
                          const int* __restrict__ src,
                          const int* __restrict__ dst,
                          const float* __restrict__ We,
                          const float* __restrict__ V,
                          const float* __restrict__ ALPHA,
                          const float* __restrict__ AMAX,
                          float* __restrict__ DENOM,
                          float* __restrict__ OUT) {
    const int e = blockIdx.x;
    const int t = threadIdx.x;
    const int s = src[e], d = dst[e];
    const int h = t >> 6;

    const float alpha = ALPHA[e * NH + h];
    const float am = AMAX[d * NH + h];   // finite: this edge contributed to it
    const float ex = expf(alpha - am);

    if ((t & 63) == 0) atomicAdd(&DENOM[d * NH + h], ex);

    float ev = 0.f;
    #pragma unroll
    for (int j = 0; j < ED; ++j) ev += ea[e * ED + j] * We[j * HC + t];

    const float vv = V[s * HC + t] + ev;
    atomicAdd(&OUT[d * HC + t], ex * vv);
}

// ---------------------------------------------------------------------------
// K4: normalize, add skip (x@Wskip), apply trailing Wlin -> d_out [N,64].
__global__ void finalize(const float* __restrict__ x,
                         const float* __restrict__ Wskip,
                         const float* __restrict__ Wlin,
                         const float* __restrict__ OUT,
                         const float* __restrict__ DENOM,
                         float* __restrict__ y) {
    __shared__ float xs[DIN];
    __shared__ float sm[HC];
    __shared__ float ps[256];
    const int n = blockIdx.x, t = threadIdx.x;
    if (t < DIN) xs[t] = x[n * DIN + t];
    __syncthreads();

    const int h = t >> 6;
    const float den = DENOM[n * NH + h];
    float val = (den > 0.f) ? OUT[n * HC + t] / den : 0.f;

    float sk = 0.f;
    for (int d = 0; d < DIN; ++d) sk += xs[d] * Wskip[d * HC + t];
    sm[t] = val + sk;
    __syncthreads();

    const int c = t & 63, q4 = t >> 6;
    float p = 0.f;
    for (int j = 0; j < 64; ++j) p += sm[q4 * 64 + j] * Wlin[(q4 * 64 + j) * CPH + c];
    ps[t] = p;
    __syncthreads();
    if (t < 64) y[n * CPH + t] = ps[t] + ps[t + 64] + ps[t + 128] + ps[t + 192];
}

// ---------------------------------------------------------------------------
extern "C" void kernel_launch(void* const* d_in, const int* in_sizes, int n_in,
                              void* d_out, int out_size, void* d_ws, size_t ws_size,
                              hipStream_t stream) {
    const float* x     = (const float*)d_in[0];
    const float* ea    = (const float*)d_in[1];
    const int*   eidx  = (const int*)  d_in[2];
    const float* Wq    = (const float*)d_in[3];
    const float* Wk    = (const float*)d_in[4];
    const float* Wv    = (const float*)d_in[5];
    const float* We    = (const float*)d_in[6];
    const float* Wskip = (const float*)d_in[7];
    const float* Wlin  = (const float*)d_in[8];
    float* out = (float*)d_out;

    float* ws    = (float*)d_ws;
    float* Q     = ws;                       // N*256
    float* K     = Q + (size_t)N_NODES * HC; // N*256
    float* V     = K + (size_t)N_NODES * HC; // N*256
    float* OUT   = V + (size_t)N_NODES * HC; // N*256
    float* AMAX  = OUT + (size_t)N_NODES * HC;   // N*4
    float* DENOM = AMAX + (size_t)N_NODES * NH;  // N*4
    float* ALPHA = DENOM + (size_t)N_NODES * NH; // E*4

    const int* src = eidx;
    const int* dst = eidx + N_EDGES;

    init_ws<<<(N_NODES * HC + 255) / 256, 256, 0, stream>>>(AMAX, DENOM, OUT);
    node_proj<<<N_NODES / RPB, 256, 0, stream>>>(x, Wq, Wk, Wv, Q, K, V);
    edge_alpha<<<N_EDGES, 256, 0, stream>>>(ea, src, dst, We, Q, K, ALPHA, AMAX);
    edge_aggr<<<N_EDGES, 256, 0, stream>>>(ea, src, dst, We, V, ALPHA, AMAX, DENOM, OUT);
    finalize<<<N_NODES, 256, 0, stream>>>(x, Wskip, Wlin, OUT, DENOM, out);
}

// Round 2
// 839.935 us; speedup vs baseline: 2.1046x; 2.1046x over previous
//
#include <hip/hip_runtime.h>
#include <math.h>

#define N_NODES 50000
#define N_EDGES 800000
#define DIN 64
#define HC 256      // H*C
#define NH 4        // heads
#define CPH 64      // channels per head
#define ED 11
#define RPB 16      // rows per block in node_proj / finalize
#define NPAD 50176  // 196*256
#define NB_SCAN 196

// ---------------------------------------------------------------------------
// K1: Q,K,V node projections. 16 nodes per 256-thread block.
__global__ void node_proj(const float* __restrict__ x,
                          const float* __restrict__ Wq,
                          const float* __restrict__ Wk,
                          const float* __restrict__ Wv,
                          float* __restrict__ Q,
                          float* __restrict__ K,
                          float* __restrict__ V) {
    __shared__ float xs[RPB * DIN];
    const int n0 = blockIdx.x * RPB;
    const int t = threadIdx.x;
    #pragma unroll
    for (int i = 0; i < 4; ++i) xs[t * 4 + i] = x[n0 * DIN + t * 4 + i];
    __syncthreads();

    float qa[RPB], ka[RPB], va[RPB];
    #pragma unroll
    for (int r = 0; r < RPB; ++r) { qa[r] = 0.f; ka[r] = 0.f; va[r] = 0.f; }

    for (int d = 0; d < DIN; ++d) {
        const float wq = Wq[d * HC + t];
        const float wk = Wk[d * HC + t];
        const float wv = Wv[d * HC + t];
        #pragma unroll
        for (int r = 0; r < RPB; ++r) {
            const float xv = xs[r * DIN + d];
            qa[r] += xv * wq;
            ka[r] += xv * wk;
            va[r] += xv * wv;
        }
    }
    #pragma unroll
    for (int r = 0; r < RPB; ++r) {
        Q[(n0 + r) * HC + t] = qa[r];
        K[(n0 + r) * HC + t] = ka[r];
        V[(n0 + r) * HC + t] = va[r];
    }
}

// ---------------------------------------------------------------------------
// CSR build: zero, histogram, 3-kernel scan, scatter.
__global__ void zero_ints(int* __restrict__ a, int n) {
    const int i = blockIdx.x * blockDim.x + threadIdx.x;
    if (i < n) a[i] = 0;
}

__global__ void hist_deg(const int* __restrict__ dst, int* __restrict__ deg) {
    const int e = blockIdx.x * blockDim.x + threadIdx.x;
    if (e < N_EDGES) atomicAdd(&deg[dst[e]], 1);
}

__global__ void scan_local(const int* __restrict__ deg, int* __restrict__ rowstart,
                           int* __restrict__ psum) {
    __shared__ int s[256];
    const int b = blockIdx.x, t = threadIdx.x, i = b * 256 + t;
    const int v = (i < N_NODES) ? deg[i] : 0;
    s[t] = v;
    __syncthreads();
    for (int off = 1; off < 256; off <<= 1) {
        const int xr = (t >= off) ? s[t - off] : 0;
        __syncthreads();
        s[t] += xr;
        __syncthreads();
    }
    if (i < N_NODES) rowstart[i] = s[t] - v;  // exclusive
    if (t == 255) psum[b] = s[255];
}

__global__ void scan_psum(int* __restrict__ psum) {  // 1 block, NB_SCAN<=256
    __shared__ int s[256];
    const int t = threadIdx.x;
    const int v = (t < NB_SCAN) ? psum[t] : 0;
    s[t] = v;
    __syncthreads();
    for (int off = 1; off < 256; off <<= 1) {
        const int xr = (t >= off) ? s[t - off] : 0;
        __syncthreads();
        s[t] += xr;
        __syncthreads();
    }
    if (t < NB_SCAN) psum[t] = s[t] - v;  // exclusive block offsets
}

__global__ void scan_add(int* __restrict__ rowstart, const int* __restrict__ psum) {
    const int i = blockIdx.x * 256 + threadIdx.x;
    if (i < N_NODES) rowstart[i] += psum[blockIdx.x];
}

__global__ void scatter_edges(const int* __restrict__ src, const int* __restrict__ dst,
                              const int* __restrict__ rowstart, int* __restrict__ cursor,
                              int* __restrict__ eperm_e, int* __restrict__ eperm_s) {
    const int e = blockIdx.x * blockDim.x + threadIdx.x;
    if (e >= N_EDGES) return;
    const int d = dst[e];
    const int pos = atomicAdd(&cursor[d], 1);
    const int idx = rowstart[d] + pos;
    eperm_e[idx] = e;
    eperm_s[idx] = src[e];
}

// ---------------------------------------------------------------------------
// K2: fused attention per destination node. Block = 256 = 4 waves = 4 heads;
// thread t owns output channel t. Online softmax in registers, zero atomics.
__global__ void attn_fused(const float* __restrict__ ea,
                           const int* __restrict__ eperm_e,
                           const int* __restrict__ eperm_s,
                           const float* __restrict__ We,
                           const float* __restrict__ Q,
                           const float* __restrict__ K,
                           const float* __restrict__ V,
                           const int* __restrict__ rowstart,
                           const int* __restrict__ deg,
                           float* __restrict__ OUT) {
    const int n = blockIdx.x, t = threadIdx.x, lane = t & 63;
    float Wcol[ED];
    #pragma unroll
    for (int j = 0; j < ED; ++j) Wcol[j] = We[j * HC + t];
    const float q = Q[n * HC + t];
    const int beg = rowstart[n], dc = deg[n];

    float m = -INFINITY, den = 0.f, acc = 0.f;
    for (int i = 0; i < dc; ++i) {
        const int idx = beg + i;
        const int e = eperm_e[idx];
        const int s = eperm_s[idx];
        // broadcast the 11 edge features via shfl (one coalesced 44B load)
        const float eav = (lane < ED) ? ea[(size_t)e * ED + lane] : 0.f;
        float ev = 0.f;
        #pragma unroll
        for (int j = 0; j < ED; ++j) ev += __shfl(eav, j, 64) * Wcol[j];

        const float kv = K[(size_t)s * HC + t] + ev;
        float p = q * kv;
        #pragma unroll
        for (int off = 32; off; off >>= 1) p += __shfl_xor(p, off, 64);
        const float alpha = p * 0.125f;  // /sqrt(64); wave-uniform

        if (alpha > m) {               // wave-uniform branch
            const float sc = __expf(m - alpha);  // expf(-inf)=0 on first hit
            acc *= sc; den *= sc; m = alpha;
        }
        const float ex = __expf(alpha - m);
        den += ex;
        acc += ex * (V[(size_t)s * HC + t] + ev);
    }
    OUT[n * HC + t] = (den > 0.f) ? acc / den : 0.f;
}

// ---------------------------------------------------------------------------
// K3: add skip (x@Wskip), apply trailing Wlin -> y [N,64]. 16 nodes/block.
__global__ void finalize16(const float* __restrict__ x,
                           const float* __restrict__ Wskip,
                           const float* __restrict__ Wlin,
                           const float* __restrict__ OUT,
                           float* __restrict__ y) {
    __shared__ float sm[RPB][HC];   // 16 KB
    __shared__ float xs[RPB][DIN];  // 4 KB
    const int n0 = blockIdx.x * RPB, t = threadIdx.x;
    #pragma unroll
    for (int i = 0; i < 4; ++i) {
        const int k = t * 4 + i;
        xs[k >> 6][k & 63] = x[n0 * DIN + k];
    }
    __syncthreads();

    float a[RPB];
    #pragma unroll
    for (int r = 0; r < RPB; ++r) a[r] = OUT[(n0 + r) * HC + t];
    for (int d = 0; d < DIN; ++d) {
        const float w = Wskip[d * HC + t];
        #pragma unroll
        for (int r = 0; r < RPB; ++r) a[r] += xs[r][d] * w;
    }
    #pragma unroll
    for (int r = 0; r < RPB; ++r) sm[r][t] = a[r];
    __syncthreads();

    const int c = t & 63, r0 = (t >> 6) * 4;
    float b[4] = {0.f, 0.f, 0.f, 0.f};
    for (int j = 0; j < HC; ++j) {
        const float w = Wlin[j * CPH + c];
        #pragma unroll
        for (int rr = 0; rr < 4; ++rr) b[rr] += sm[r0 + rr][j] * w;
    }
    #pragma unroll
    for (int rr = 0; rr < 4; ++rr) y[(n0 + r0 + rr) * CPH + c] = b[rr];
}

// ---------------------------------------------------------------------------
extern "C" void kernel_launch(void* const* d_in, const int* in_sizes, int n_in,
                              void* d_out, int out_size, void* d_ws, size_t ws_size,
                              hipStream_t stream) {
    const float* x     = (const float*)d_in[0];
    const float* ea    = (const float*)d_in[1];
    const int*   eidx  = (const int*)  d_in[2];
    const float* Wq    = (const float*)d_in[3];
    const float* Wk    = (const float*)d_in[4];
    const float* Wv    = (const float*)d_in[5];
    const float* We    = (const float*)d_in[6];
    const float* Wskip = (const float*)d_in[7];
    const float* Wlin  = (const float*)d_in[8];
    float* out = (float*)d_out;

    float* ws  = (float*)d_ws;
    float* Q   = ws;                          // N*256
    float* K   = Q + (size_t)N_NODES * HC;    // N*256
    float* V   = K + (size_t)N_NODES * HC;    // N*256
    float* OUT = V + (size_t)N_NODES * HC;    // N*256
    int* ibase   = (int*)(OUT + (size_t)N_NODES * HC);
    int* deg     = ibase;              // NPAD
    int* rowstart= deg + NPAD;         // NPAD
    int* cursor  = rowstart + NPAD;    // NPAD
    int* psum    = cursor + NPAD;      // 256
    int* eperm_e = psum + 256;         // E
    int* eperm_s = eperm_e + N_EDGES;  // E

    const int* src = eidx;
    const int* dst = eidx + N_EDGES;

    // CSR build
    zero_ints<<<(2 * NPAD + 255) / 256, 256, 0, stream>>>(deg, 2 * NPAD); // deg+rowstart? (deg,cursor adjacent? no)
    zero_ints<<<(NPAD + 255) / 256, 256, 0, stream>>>(cursor, NPAD);
    hist_deg<<<(N_EDGES + 255) / 256, 256, 0, stream>>>(dst, deg);
    scan_local<<<NB_SCAN, 256, 0, stream>>>(deg, rowstart, psum);
    scan_psum<<<1, 256, 0, stream>>>(psum);
    scan_add<<<NB_SCAN, 256, 0, stream>>>(rowstart, psum);
    scatter_edges<<<(N_EDGES + 255) / 256, 256, 0, stream>>>(src, dst, rowstart, cursor,
                                                             eperm_e, eperm_s);
    // dense pipeline
    node_proj<<<N_NODES / RPB, 256, 0, stream>>>(x, Wq, Wk, Wv, Q, K, V);
    attn_fused<<<N_NODES, 256, 0, stream>>>(ea, eperm_e, eperm_s, We, Q, K, V,
                                            rowstart, deg, OUT);
    finalize16<<<N_NODES / RPB, 256, 0, stream>>>(x, Wskip, Wlin, OUT, out);
}

// Round 3
// 684.373 us; speedup vs baseline: 2.5829x; 1.2273x over previous
//
#include <hip/hip_runtime.h>
#include <math.h>

#define N_NODES 50000
#define N_EDGES 800000
#define DIN 64
#define HC 256      // H*C
#define NH 4        // heads
#define CPH 64      // channels per head
#define ED 11
#define RPB 16      // rows per block in node_proj / finalize
#define NPAD 50176  // 196*256
#define NB_SCAN 196
#define CHUNK 16
#define EPW 4       // edges per wave in attn phase 1

// ---------------------------------------------------------------------------
// K1: Q,K,V node projections. 16 nodes per 256-thread block.
__global__ void node_proj(const float* __restrict__ x,
                          const float* __restrict__ Wq,
                          const float* __restrict__ Wk,
                          const float* __restrict__ Wv,
                          float* __restrict__ Q,
                          float* __restrict__ K,
                          float* __restrict__ V) {
    __shared__ float xs[RPB * DIN];
    const int n0 = blockIdx.x * RPB;
    const int t = threadIdx.x;
    #pragma unroll
    for (int i = 0; i < 4; ++i) xs[t * 4 + i] = x[n0 * DIN + t * 4 + i];
    __syncthreads();

    float qa[RPB], ka[RPB], va[RPB];
    #pragma unroll
    for (int r = 0; r < RPB; ++r) { qa[r] = 0.f; ka[r] = 0.f; va[r] = 0.f; }

    for (int d = 0; d < DIN; ++d) {
        const float wq = Wq[d * HC + t];
        const float wk = Wk[d * HC + t];
        const float wv = Wv[d * HC + t];
        #pragma unroll
        for (int r = 0; r < RPB; ++r) {
            const float xv = xs[r * DIN + d];
            qa[r] += xv * wq;
            ka[r] += xv * wk;
            va[r] += xv * wv;
        }
    }
    #pragma unroll
    for (int r = 0; r < RPB; ++r) {
        Q[(n0 + r) * HC + t] = qa[r];
        K[(n0 + r) * HC + t] = ka[r];
        V[(n0 + r) * HC + t] = va[r];
    }
}

// ---------------------------------------------------------------------------
// CSR build: zero, histogram, 3-kernel scan, scatter.
__global__ void zero_ints(int* __restrict__ a, int n) {
    const int i = blockIdx.x * blockDim.x + threadIdx.x;
    if (i < n) a[i] = 0;
}

__global__ void hist_deg(const int* __restrict__ dst, int* __restrict__ deg) {
    const int e = blockIdx.x * blockDim.x + threadIdx.x;
    if (e < N_EDGES) atomicAdd(&deg[dst[e]], 1);
}

__global__ void scan_local(const int* __restrict__ deg, int* __restrict__ rowstart,
                           int* __restrict__ psum) {
    __shared__ int s[256];
    const int b = blockIdx.x, t = threadIdx.x, i = b * 256 + t;
    const int v = (i < N_NODES) ? deg[i] : 0;
    s[t] = v;
    __syncthreads();
    for (int off = 1; off < 256; off <<= 1) {
        const int xr = (t >= off) ? s[t - off] : 0;
        __syncthreads();
        s[t] += xr;
        __syncthreads();
    }
    if (i < N_NODES) rowstart[i] = s[t] - v;  // exclusive
    if (t == 255) psum[b] = s[255];
}

__global__ void scan_psum(int* __restrict__ psum) {  // 1 block, NB_SCAN<=256
    __shared__ int s[256];
    const int t = threadIdx.x;
    const int v = (t < NB_SCAN) ? psum[t] : 0;
    s[t] = v;
    __syncthreads();
    for (int off = 1; off < 256; off <<= 1) {
        const int xr = (t >= off) ? s[t - off] : 0;
        __syncthreads();
        s[t] += xr;
        __syncthreads();
    }
    if (t < NB_SCAN) psum[t] = s[t] - v;  // exclusive block offsets
}

__global__ void scan_add(int* __restrict__ rowstart, const int* __restrict__ psum) {
    const int i = blockIdx.x * 256 + threadIdx.x;
    if (i < N_NODES) rowstart[i] += psum[blockIdx.x];
}

__global__ void scatter_edges(const int* __restrict__ src, const int* __restrict__ dst,
                              const int* __restrict__ rowstart, int* __restrict__ cursor,
                              int* __restrict__ eperm_e, int* __restrict__ eperm_s) {
    const int e = blockIdx.x * blockDim.x + threadIdx.x;
    if (e >= N_EDGES) return;
    const int d = dst[e];
    const int pos = atomicAdd(&cursor[d], 1);
    const int idx = rowstart[d] + pos;
    eperm_e[idx] = e;
    eperm_s[idx] = src[e];
}

// ---------------------------------------------------------------------------
// K2: fused attention, chunked two-phase. Block = 256 threads = 1 dst node.
// Phase 1 (per wave, EPW edges): e-projection (float4 lanes, We in regs,
//   scalar ea loads) + 4-step 16-lane dot reduce -> EV & alpha in LDS.
// Phase 2 (per thread = channel): chunk max, one rescale/chunk, 16 unrolled
//   independent accumulate iterations.
__global__ void attn_fused2(const float* __restrict__ ea,
                            const int* __restrict__ eperm_e,
                            const int* __restrict__ eperm_s,
                            const float* __restrict__ We,
                            const float* __restrict__ Q,
                            const float* __restrict__ K,
                            const float* __restrict__ V,
                            const int* __restrict__ rowstart,
                            const int* __restrict__ deg,
                            float* __restrict__ OUT) {
    __shared__ float EV[CHUNK][HC];   // 16 KB
    __shared__ float AL[NH][CHUNK];   // 256 B, alpha transposed [head][slot]
    __shared__ int   SRC[CHUNK];

    const int n = blockIdx.x;
    const int t = threadIdx.x;
    const int lane = t & 63;
    const int wid = t >> 6;

    // phase-1 mapping: lane owns channels lane*4..lane*4+3 (head = lane>>4)
    const float4 q4 = ((const float4*)Q)[n * 64 + lane];
    float4 We4[ED];
    #pragma unroll
    for (int j = 0; j < ED; ++j) We4[j] = ((const float4*)We)[j * 64 + lane];

    const int beg = rowstart[n];
    const int dc  = deg[n];

    float m = -INFINITY, den = 0.f, acc = 0.f;

    for (int cbase = 0; cbase < dc; cbase += CHUNK) {
        // ---------------- phase 1 ----------------
        #pragma unroll
        for (int ii = 0; ii < EPW; ++ii) {
            const int slot = wid * EPW + ii;
            const int g = cbase + slot;
            if (g < dc) {
                const int idx = beg + g;
                const int e = __builtin_amdgcn_readfirstlane(eperm_e[idx]);
                const int s = __builtin_amdgcn_readfirstlane(eperm_s[idx]);
                if (lane == 0) SRC[slot] = s;
                float4 ev = {0.f, 0.f, 0.f, 0.f};
                #pragma unroll
                for (int j = 0; j < ED; ++j) {
                    const float a = ea[(size_t)e * ED + j];  // scalar load
                    ev.x = fmaf(a, We4[j].x, ev.x);
                    ev.y = fmaf(a, We4[j].y, ev.y);
                    ev.z = fmaf(a, We4[j].z, ev.z);
                    ev.w = fmaf(a, We4[j].w, ev.w);
                }
                ((float4*)&EV[slot][0])[lane] = ev;
                const float4 k4 = ((const float4*)K)[(size_t)s * 64 + lane];
                float p = q4.x * (k4.x + ev.x) + q4.y * (k4.y + ev.y)
                        + q4.z * (k4.z + ev.z) + q4.w * (k4.w + ev.w);
                p += __shfl_xor(p, 1, 64);
                p += __shfl_xor(p, 2, 64);
                p += __shfl_xor(p, 4, 64);
                p += __shfl_xor(p, 8, 64);
                if ((lane & 15) == 0) AL[lane >> 4][slot] = p * 0.125f;
            } else {
                if (lane == 0) SRC[slot] = 0;  // safe gather target for padding
                if ((lane & 15) == 0) AL[lane >> 4][slot] = -INFINITY;
            }
        }
        __syncthreads();

        // ---------------- phase 2 ----------------
        const float4 a0 = ((const float4*)&AL[wid][0])[0];
        const float4 a1 = ((const float4*)&AL[wid][0])[1];
        const float4 a2 = ((const float4*)&AL[wid][0])[2];
        const float4 a3 = ((const float4*)&AL[wid][0])[3];
        const float al[CHUNK] = {a0.x, a0.y, a0.z, a0.w, a1.x, a1.y, a1.z, a1.w,
                                 a2.x, a2.y, a2.z, a2.w, a3.x, a3.y, a3.z, a3.w};
        float cm = al[0];
        #pragma unroll
        for (int i = 1; i < CHUNK; ++i) cm = fmaxf(cm, al[i]);
        const float mn = fmaxf(m, cm);
        const float sc = __expf(m - mn);  // first chunk: exp(-inf)=0
        acc *= sc; den *= sc; m = mn;

        #pragma unroll
        for (int i = 0; i < CHUNK; ++i) {
            const float ex = __expf(al[i] - m);   // padding: exp(-inf)=0
            const float vv = V[(size_t)SRC[i] * HC + t] + EV[i][t];
            acc = fmaf(ex, vv, acc);
            den += ex;
        }
        __syncthreads();  // protect LDS before next chunk's phase 1
    }

    OUT[n * HC + t] = (den > 0.f) ? acc / den : 0.f;
}

// ---------------------------------------------------------------------------
// K3: add skip (x@Wskip), apply trailing Wlin -> y [N,64]. 16 nodes/block.
__global__ void finalize16(const float* __restrict__ x,
                           const float* __restrict__ Wskip,
                           const float* __restrict__ Wlin,
                           const float* __restrict__ OUT,
                           float* __restrict__ y) {
    __shared__ float sm[RPB][HC];   // 16 KB
    __shared__ float xs[RPB][DIN];  // 4 KB
    const int n0 = blockIdx.x * RPB, t = threadIdx.x;
    #pragma unroll
    for (int i = 0; i < 4; ++i) {
        const int k = t * 4 + i;
        xs[k >> 6][k & 63] = x[n0 * DIN + k];
    }
    __syncthreads();

    float a[RPB];
    #pragma unroll
    for (int r = 0; r < RPB; ++r) a[r] = OUT[(n0 + r) * HC + t];
    for (int d = 0; d < DIN; ++d) {
        const float w = Wskip[d * HC + t];
        #pragma unroll
        for (int r = 0; r < RPB; ++r) a[r] += xs[r][d] * w;
    }
    #pragma unroll
    for (int r = 0; r < RPB; ++r) sm[r][t] = a[r];
    __syncthreads();

    const int c = t & 63, r0 = (t >> 6) * 4;
    float b[4] = {0.f, 0.f, 0.f, 0.f};
    for (int j = 0; j < HC; ++j) {
        const float w = Wlin[j * CPH + c];
        #pragma unroll
        for (int rr = 0; rr < 4; ++rr) b[rr] += sm[r0 + rr][j] * w;
    }
    #pragma unroll
    for (int rr = 0; rr < 4; ++rr) y[(n0 + r0 + rr) * CPH + c] = b[rr];
}

// ---------------------------------------------------------------------------
extern "C" void kernel_launch(void* const* d_in, const int* in_sizes, int n_in,
                              void* d_out, int out_size, void* d_ws, size_t ws_size,
                              hipStream_t stream) {
    const float* x     = (const float*)d_in[0];
    const float* ea    = (const float*)d_in[1];
    const int*   eidx  = (const int*)  d_in[2];
    const float* Wq    = (const float*)d_in[3];
    const float* Wk    = (const float*)d_in[4];
    const float* Wv    = (const float*)d_in[5];
    const float* We    = (const float*)d_in[6];
    const float* Wskip = (const float*)d_in[7];
    const float* Wlin  = (const float*)d_in[8];
    float* out = (float*)d_out;

    float* ws  = (float*)d_ws;
    float* Q   = ws;                          // N*256
    float* K   = Q + (size_t)N_NODES * HC;    // N*256
    float* V   = K + (size_t)N_NODES * HC;    // N*256
    float* OUT = V + (size_t)N_NODES * HC;    // N*256
    int* ibase   = (int*)(OUT + (size_t)N_NODES * HC);
    int* deg     = ibase;              // NPAD
    int* rowstart= deg + NPAD;         // NPAD
    int* cursor  = rowstart + NPAD;    // NPAD
    int* psum    = cursor + NPAD;      // 256
    int* eperm_e = psum + 256;         // E
    int* eperm_s = eperm_e + N_EDGES;  // E

    const int* src = eidx;
    const int* dst = eidx + N_EDGES;

    // CSR build (deg, rowstart, cursor are contiguous -> one zero pass)
    zero_ints<<<(3 * NPAD + 255) / 256, 256, 0, stream>>>(deg, 3 * NPAD);
    hist_deg<<<(N_EDGES + 255) / 256, 256, 0, stream>>>(dst, deg);
    scan_local<<<NB_SCAN, 256, 0, stream>>>(deg, rowstart, psum);
    scan_psum<<<1, 256, 0, stream>>>(psum);
    scan_add<<<NB_SCAN, 256, 0, stream>>>(rowstart, psum);
    scatter_edges<<<(N_EDGES + 255) / 256, 256, 0, stream>>>(src, dst, rowstart, cursor,
                                                             eperm_e, eperm_s);
    // dense pipeline
    node_proj<<<N_NODES / RPB, 256, 0, stream>>>(x, Wq, Wk, Wv, Q, K, V);
    attn_fused2<<<N_NODES, 256, 0, stream>>>(ea, eperm_e, eperm_s, We, Q, K, V,
                                             rowstart, deg, OUT);
    finalize16<<<N_NODES / RPB, 256, 0, stream>>>(x, Wskip, Wlin, OUT, out);
}

// Round 4
// 593.383 us; speedup vs baseline: 2.9790x; 1.1533x over previous
//
#include <hip/hip_runtime.h>
#include <math.h>

#define N_NODES 50000
#define N_EDGES 800000
#define DIN 64
#define HC 256      // H*C
#define NH 4        // heads
#define CPH 64      // channels per head
#define ED 11
#define RPB 16      // rows per block in node_proj / finalize
#define NPAD 50176  // 196*256
#define NB_SCAN 196
#define CHUNK 16
#define EPW 4       // edges per wave in attn phase 1

typedef unsigned int uint;
typedef unsigned short ushort_t;

__device__ __forceinline__ ushort_t f2bf(float f) {
    uint u = __float_as_uint(f);
    u = (u + 0x7FFFu + ((u >> 16) & 1u)) >> 16;   // RTNE
    return (ushort_t)u;
}
__device__ __forceinline__ float bf2f(ushort_t h) {
    return __uint_as_float(((uint)h) << 16);
}

// ---------------------------------------------------------------------------
// M2[d][hj] = sum_c Wq[d, h*64+c] * We[j, h*64+c], hj = h*11+j (<44), else 0.
__global__ void make_m2(const float* __restrict__ Wq, const float* __restrict__ We,
                        float* __restrict__ M2) {
    const int g = blockIdx.x * 256 + threadIdx.x;
    if (g >= 64 * 64) return;
    const int d = g >> 6, hj = g & 63;
    float v = 0.f;
    if (hj < 44) {
        const int h = hj / 11, j = hj - h * 11;
        const float* wq = Wq + d * HC + h * 64;
        const float* we = We + j * HC + h * 64;
        #pragma unroll 8
        for (int c = 0; c < 64; ++c) v = fmaf(wq[c], we[c], v);
    }
    M2[g] = v;
}

// ---------------------------------------------------------------------------
// K1: Q (f32) + Kb,Vb (bf16) projections + QWE = x @ M2. 16 nodes/block.
__global__ void node_proj(const float* __restrict__ x,
                          const float* __restrict__ Wq,
                          const float* __restrict__ Wk,
                          const float* __restrict__ Wv,
                          const float* __restrict__ M2,
                          float* __restrict__ Q,
                          ushort_t* __restrict__ Kb,
                          ushort_t* __restrict__ Vb,
                          float* __restrict__ QWE) {
    __shared__ float xs[RPB * DIN];
    const int n0 = blockIdx.x * RPB;
    const int t = threadIdx.x;
    const int lane = t & 63, wid = t >> 6;
    #pragma unroll
    for (int i = 0; i < 4; ++i) xs[t * 4 + i] = x[n0 * DIN + t * 4 + i];
    __syncthreads();

    float qa[RPB], ka[RPB], va[RPB];
    #pragma unroll
    for (int r = 0; r < RPB; ++r) { qa[r] = 0.f; ka[r] = 0.f; va[r] = 0.f; }
    float qwe[4] = {0.f, 0.f, 0.f, 0.f};
    const int rbase = wid * 4;

    for (int d = 0; d < DIN; ++d) {
        const float wq = Wq[d * HC + t];
        const float wk = Wk[d * HC + t];
        const float wv = Wv[d * HC + t];
        #pragma unroll
        for (int r = 0; r < RPB; ++r) {
            const float xv = xs[r * DIN + d];
            qa[r] = fmaf(xv, wq, qa[r]);
            ka[r] = fmaf(xv, wk, ka[r]);
            va[r] = fmaf(xv, wv, va[r]);
        }
        const float m2 = M2[d * 64 + lane];
        #pragma unroll
        for (int rr = 0; rr < 4; ++rr)
            qwe[rr] = fmaf(xs[(rbase + rr) * DIN + d], m2, qwe[rr]);
    }
    #pragma unroll
    for (int r = 0; r < RPB; ++r) {
        Q [(size_t)(n0 + r) * HC + t] = qa[r];
        Kb[(size_t)(n0 + r) * HC + t] = f2bf(ka[r]);
        Vb[(size_t)(n0 + r) * HC + t] = f2bf(va[r]);
    }
    if (lane < 44) {
        #pragma unroll
        for (int rr = 0; rr < 4; ++rr)
            QWE[(size_t)(n0 + rbase + rr) * 44 + lane] = qwe[rr];
    }
}

// ---------------------------------------------------------------------------
// CSR build: zero, histogram, 3-kernel scan, scatter.
__global__ void zero_ints(int* __restrict__ a, int n) {
    const int i = blockIdx.x * blockDim.x + threadIdx.x;
    if (i < n) a[i] = 0;
}

__global__ void hist_deg(const int* __restrict__ dst, int* __restrict__ deg) {
    const int e = blockIdx.x * blockDim.x + threadIdx.x;
    if (e < N_EDGES) atomicAdd(&deg[dst[e]], 1);
}

__global__ void scan_local(const int* __restrict__ deg, int* __restrict__ rowstart,
                           int* __restrict__ psum) {
    __shared__ int s[256];
    const int b = blockIdx.x, t = threadIdx.x, i = b * 256 + t;
    const int v = (i < N_NODES) ? deg[i] : 0;
    s[t] = v;
    __syncthreads();
    for (int off = 1; off < 256; off <<= 1) {
        const int xr = (t >= off) ? s[t - off] : 0;
        __syncthreads();
        s[t] += xr;
        __syncthreads();
    }
    if (i < N_NODES) rowstart[i] = s[t] - v;  // exclusive
    if (t == 255) psum[b] = s[255];
}

__global__ void scan_psum(int* __restrict__ psum) {  // 1 block, NB_SCAN<=256
    __shared__ int s[256];
    const int t = threadIdx.x;
    const int v = (t < NB_SCAN) ? psum[t] : 0;
    s[t] = v;
    __syncthreads();
    for (int off = 1; off < 256; off <<= 1) {
        const int xr = (t >= off) ? s[t - off] : 0;
        __syncthreads();
        s[t] += xr;
        __syncthreads();
    }
    if (t < NB_SCAN) psum[t] = s[t] - v;  // exclusive block offsets
}

__global__ void scan_add(int* __restrict__ rowstart, const int* __restrict__ psum) {
    const int i = blockIdx.x * 256 + threadIdx.x;
    if (i < N_NODES) rowstart[i] += psum[blockIdx.x];
}

__global__ void scatter_edges(const int* __restrict__ src, const int* __restrict__ dst,
                              const int* __restrict__ rowstart, int* __restrict__ cursor,
                              int* __restrict__ eperm_e, int* __restrict__ eperm_s) {
    const int e = blockIdx.x * blockDim.x + threadIdx.x;
    if (e >= N_EDGES) return;
    const int d = dst[e];
    const int pos = atomicAdd(&cursor[d], 1);
    const int idx = rowstart[d] + pos;
    eperm_e[idx] = e;
    eperm_s[idx] = src[e];
}

// ---------------------------------------------------------------------------
// K2: fused attention, deferred e-projection, bf16 K/V gathers.
// Block = 256 threads = 1 dst node. Phase 1: per wave 4 edges, qk dot (bf16 K)
// + alpha += ea.QWE. Phase 2: per thread = channel, online softmax + ex*V
// accumulate; lanes<11 also accumulate T[h][j] = sum ex*ea[j].
__global__ void attn3(const float* __restrict__ ea,
                      const int* __restrict__ eperm_e,
                      const int* __restrict__ eperm_s,
                      const float* __restrict__ Q,
                      const float* __restrict__ QWE,
                      const ushort_t* __restrict__ Kb,
                      const ushort_t* __restrict__ Vb,
                      const int* __restrict__ rowstart,
                      const int* __restrict__ deg,
                      float* __restrict__ OUT,
                      float* __restrict__ TO) {
    __shared__ float AL[NH][CHUNK];   // alpha transposed [head][slot]
    __shared__ float EA[CHUNK][12];   // raw edge features (pad 12)
    __shared__ int   SRC[CHUNK];

    const int n = blockIdx.x;
    const int t = threadIdx.x;
    const int lane = t & 63;
    const int wid = t >> 6;
    const int hp1 = lane >> 4;  // phase-1 head for this lane

    const float4 q4 = ((const float4*)Q)[(size_t)n * 64 + lane];
    float qwej[ED];
    #pragma unroll
    for (int j = 0; j < ED; ++j) qwej[j] = QWE[(size_t)n * 44 + hp1 * 11 + j];

    const int beg = __builtin_amdgcn_readfirstlane(rowstart[n]);
    const int dc  = __builtin_amdgcn_readfirstlane(deg[n]);

    float m = -INFINITY, den = 0.f, acc = 0.f, Tacc = 0.f;

    for (int cbase = 0; cbase < dc; cbase += CHUNK) {
        // ---------------- phase 1 ----------------
        #pragma unroll
        for (int ii = 0; ii < EPW; ++ii) {
            const int slot = wid * EPW + ii;
            const int g = cbase + slot;
            if (g < dc) {
                const int idx = beg + g;
                const int e = eperm_e[idx];   // uniform address -> s_load
                const int s = eperm_s[idx];
                if (lane == 0) SRC[slot] = s;
                if (lane < ED) EA[slot][lane] = ea[(size_t)e * ED + lane];
                const ushort4 kb4 = ((const ushort4*)(Kb + (size_t)s * HC))[lane];
                float p = q4.x * bf2f(kb4.x) + q4.y * bf2f(kb4.y)
                        + q4.z * bf2f(kb4.z) + q4.w * bf2f(kb4.w);
                p += __shfl_xor(p, 1, 64);
                p += __shfl_xor(p, 2, 64);
                p += __shfl_xor(p, 4, 64);
                p += __shfl_xor(p, 8, 64);
                float eaq = 0.f;
                #pragma unroll
                for (int j = 0; j < ED; ++j) eaq = fmaf(EA[slot][j], qwej[j], eaq);
                if ((lane & 15) == 0) AL[hp1][slot] = (p + eaq) * 0.125f;
            } else {
                if (lane == 0) SRC[slot] = 0;
                if (lane < ED) EA[slot][lane] = 0.f;
                if ((lane & 15) == 0) AL[hp1][slot] = -INFINITY;
            }
        }
        __syncthreads();

        // ---------------- phase 2 ----------------
        float al[CHUNK];
        {
            const float4 a0 = ((const float4*)&AL[wid][0])[0];
            const float4 a1 = ((const float4*)&AL[wid][0])[1];
            const float4 a2 = ((const float4*)&AL[wid][0])[2];
            const float4 a3 = ((const float4*)&AL[wid][0])[3];
            al[0]=a0.x; al[1]=a0.y; al[2]=a0.z; al[3]=a0.w;
            al[4]=a1.x; al[5]=a1.y; al[6]=a1.z; al[7]=a1.w;
            al[8]=a2.x; al[9]=a2.y; al[10]=a2.z; al[11]=a2.w;
            al[12]=a3.x; al[13]=a3.y; al[14]=a3.z; al[15]=a3.w;
        }
        float cm = al[0];
        #pragma unroll
        for (int i = 1; i < CHUNK; ++i) cm = fmaxf(cm, al[i]);
        const float mn = fmaxf(m, cm);
        const float sc = __expf(m - mn);  // first chunk: exp(-inf)=0
        acc *= sc; den *= sc; Tacc *= sc; m = mn;

        #pragma unroll
        for (int i = 0; i < CHUNK; ++i) {
            const float ex = __expf(al[i] - m);   // padding: exp(-inf)=0
            den += ex;
            const float vv = bf2f(Vb[(size_t)SRC[i] * HC + t]);
            acc = fmaf(ex, vv, acc);
            if (lane < ED) Tacc = fmaf(ex, EA[i][lane], Tacc);
        }
        __syncthreads();  // protect LDS before next chunk's phase 1
    }

    const float inv = (den > 0.f) ? 1.f / den : 0.f;
    OUT[(size_t)n * HC + t] = acc * inv;
    if (lane < ED) TO[(size_t)n * 44 + wid * 11 + lane] = Tacc * inv;
}

// ---------------------------------------------------------------------------
// K3: out = (OUT + TO@We + x@Wskip) @ Wlin. 16 nodes/block.
__global__ void finalize16(const float* __restrict__ x,
                           const float* __restrict__ Wskip,
                           const float* __restrict__ Wlin,
                           const float* __restrict__ We,
                           const float* __restrict__ OUT,
                           const float* __restrict__ TO,
                           float* __restrict__ y) {
    __shared__ float sm[RPB][HC];    // 16 KB
    __shared__ float xs[RPB][DIN];   // 4 KB
    __shared__ float tos[RPB * 44];  // 2.8 KB
    const int n0 = blockIdx.x * RPB, t = threadIdx.x;
    const int h = t >> 6;
    #pragma unroll
    for (int i = 0; i < 4; ++i) {
        const int k = t * 4 + i;
        xs[k >> 6][k & 63] = x[n0 * DIN + k];
    }
    for (int i = t; i < RPB * 44; i += 256) tos[i] = TO[(size_t)n0 * 44 + i];
    __syncthreads();

    float w11[ED];
    #pragma unroll
    for (int j = 0; j < ED; ++j) w11[j] = We[j * HC + t];

    float a[RPB];
    #pragma unroll
    for (int r = 0; r < RPB; ++r) {
        a[r] = OUT[(size_t)(n0 + r) * HC + t];
        #pragma unroll
        for (int j = 0; j < ED; ++j)
            a[r] = fmaf(tos[r * 44 + h * 11 + j], w11[j], a[r]);
    }
    for (int d = 0; d < DIN; ++d) {
        const float w = Wskip[d * HC + t];
        #pragma unroll
        for (int r = 0; r < RPB; ++r) a[r] = fmaf(xs[r][d], w, a[r]);
    }
    #pragma unroll
    for (int r = 0; r < RPB; ++r) sm[r][t] = a[r];
    __syncthreads();

    const int c = t & 63, r0 = (t >> 6) * 4;
    float b[4] = {0.f, 0.f, 0.f, 0.f};
    for (int j = 0; j < HC; ++j) {
        const float w = Wlin[j * CPH + c];
        #pragma unroll
        for (int rr = 0; rr < 4; ++rr) b[rr] = fmaf(sm[r0 + rr][j], w, b[rr]);
    }
    #pragma unroll
    for (int rr = 0; rr < 4; ++rr) y[(size_t)(n0 + r0 + rr) * CPH + c] = b[rr];
}

// ---------------------------------------------------------------------------
extern "C" void kernel_launch(void* const* d_in, const int* in_sizes, int n_in,
                              void* d_out, int out_size, void* d_ws, size_t ws_size,
                              hipStream_t stream) {
    const float* x     = (const float*)d_in[0];
    const float* ea    = (const float*)d_in[1];
    const int*   eidx  = (const int*)  d_in[2];
    const float* Wq    = (const float*)d_in[3];
    const float* Wk    = (const float*)d_in[4];
    const float* Wv    = (const float*)d_in[5];
    const float* We    = (const float*)d_in[6];
    const float* Wskip = (const float*)d_in[7];
    const float* Wlin  = (const float*)d_in[8];
    float* out = (float*)d_out;

    float* ws   = (float*)d_ws;
    float* Q    = ws;                           // N*256 f32
    float* OUT  = Q   + (size_t)N_NODES * HC;   // N*256 f32
    float* QWE  = OUT + (size_t)N_NODES * HC;   // N*44 f32
    float* TO   = QWE + (size_t)N_NODES * 44;   // N*44 f32
    float* M2   = TO  + (size_t)N_NODES * 44;   // 64*64 f32
    ushort_t* Kb = (ushort_t*)(M2 + 64 * 64);   // N*256 bf16
    ushort_t* Vb = Kb + (size_t)N_NODES * HC;   // N*256 bf16
    int* deg     = (int*)(Vb + (size_t)N_NODES * HC);
    int* rowstart= deg + NPAD;
    int* cursor  = rowstart + NPAD;
    int* psum    = cursor + NPAD;
    int* eperm_e = psum + 256;
    int* eperm_s = eperm_e + N_EDGES;

    const int* src = eidx;
    const int* dst = eidx + N_EDGES;

    // small precompute + CSR build
    make_m2<<<16, 256, 0, stream>>>(Wq, We, M2);
    zero_ints<<<(3 * NPAD + 255) / 256, 256, 0, stream>>>(deg, 3 * NPAD);
    hist_deg<<<(N_EDGES + 255) / 256, 256, 0, stream>>>(dst, deg);
    scan_local<<<NB_SCAN, 256, 0, stream>>>(deg, rowstart, psum);
    scan_psum<<<1, 256, 0, stream>>>(psum);
    scan_add<<<NB_SCAN, 256, 0, stream>>>(rowstart, psum);
    scatter_edges<<<(N_EDGES + 255) / 256, 256, 0, stream>>>(src, dst, rowstart, cursor,
                                                             eperm_e, eperm_s);
    // dense pipeline
    node_proj<<<N_NODES / RPB, 256, 0, stream>>>(x, Wq, Wk, Wv, M2, Q, Kb, Vb, QWE);
    attn3<<<N_NODES, 256, 0, stream>>>(ea, eperm_e, eperm_s, Q, QWE, Kb, Vb,
                                       rowstart, deg, OUT, TO);
    finalize16<<<N_NODES / RPB, 256, 0, stream>>>(x, Wskip, Wlin, We, OUT, TO, out);
}

// Round 5
// 477.378 us; speedup vs baseline: 3.7029x; 1.2430x over previous
//
#include <hip/hip_runtime.h>
#include <math.h>

#define N_NODES 50000
#define N_EDGES 800000
#define DIN 64
#define HC 256      // H*C
#define NH 4        // heads
#define CPH 64      // channels per head
#define ED 11
#define RPB 16      // rows per block in node_proj / finalize
#define NPAD 50176  // 196*256
#define NB_SCAN 196

typedef unsigned int uint;
typedef unsigned short ushort_t;

__device__ __forceinline__ ushort_t f2bf(float f) {
    uint u = __float_as_uint(f);
    u = (u + 0x7FFFu + ((u >> 16) & 1u)) >> 16;   // RTNE
    return (ushort_t)u;
}
__device__ __forceinline__ float bf2f(ushort_t h) {
    return __uint_as_float(((uint)h) << 16);
}
__device__ __forceinline__ float dot4(float4 a, float4 b) {
    return a.x * b.x + a.y * b.y + a.z * b.z + a.w * b.w;
}

// ---------------------------------------------------------------------------
// M2[d][hj] = sum_c Wq[d, h*64+c] * We[j, h*64+c], hj = h*11+j (<44), else 0.
__global__ void make_m2(const float* __restrict__ Wq, const float* __restrict__ We,
                        float* __restrict__ M2) {
    const int g = blockIdx.x * 256 + threadIdx.x;
    if (g >= 64 * 64) return;
    const int d = g >> 6, hj = g & 63;
    float v = 0.f;
    if (hj < 44) {
        const int h = hj / 11, j = hj - h * 11;
        const float* wq = Wq + d * HC + h * 64;
        const float* we = We + j * HC + h * 64;
        #pragma unroll 8
        for (int c = 0; c < 64; ++c) v = fmaf(wq[c], we[c], v);
    }
    M2[g] = v;
}

// ---------------------------------------------------------------------------
// K1: Q (f32) + Kb,Vb (bf16) projections + QWE = x @ M2. 16 nodes/block.
// xs read as float4 (ds_read_b128 broadcast), weights scalar-coalesced.
__global__ void node_proj(const float* __restrict__ x,
                          const float* __restrict__ Wq,
                          const float* __restrict__ Wk,
                          const float* __restrict__ Wv,
                          const float* __restrict__ M2,
                          float* __restrict__ Q,
                          ushort_t* __restrict__ Kb,
                          ushort_t* __restrict__ Vb,
                          float* __restrict__ QWE) {
    __shared__ float xs[RPB][DIN];
    const int n0 = blockIdx.x * RPB;
    const int t = threadIdx.x;
    const int lane = t & 63, wid = t >> 6;
    const int rbase = wid * 4;
    #pragma unroll
    for (int i = 0; i < 4; ++i) {
        const int k = t * 4 + i;
        xs[k >> 6][k & 63] = x[n0 * DIN + k];
    }
    __syncthreads();

    float qa[RPB], ka[RPB], va[RPB];
    #pragma unroll
    for (int r = 0; r < RPB; ++r) { qa[r] = 0.f; ka[r] = 0.f; va[r] = 0.f; }
    float qwe[4] = {0.f, 0.f, 0.f, 0.f};

    for (int d4 = 0; d4 < DIN; d4 += 4) {
        float4 wq, wk, wv, m2;
        wq.x = Wq[(d4 + 0) * HC + t]; wq.y = Wq[(d4 + 1) * HC + t];
        wq.z = Wq[(d4 + 2) * HC + t]; wq.w = Wq[(d4 + 3) * HC + t];
        wk.x = Wk[(d4 + 0) * HC + t]; wk.y = Wk[(d4 + 1) * HC + t];
        wk.z = Wk[(d4 + 2) * HC + t]; wk.w = Wk[(d4 + 3) * HC + t];
        wv.x = Wv[(d4 + 0) * HC + t]; wv.y = Wv[(d4 + 1) * HC + t];
        wv.z = Wv[(d4 + 2) * HC + t]; wv.w = Wv[(d4 + 3) * HC + t];
        m2.x = M2[(d4 + 0) * 64 + lane]; m2.y = M2[(d4 + 1) * 64 + lane];
        m2.z = M2[(d4 + 2) * 64 + lane]; m2.w = M2[(d4 + 3) * 64 + lane];
        #pragma unroll
        for (int r = 0; r < RPB; ++r) {
            const float4 xv = *(const float4*)&xs[r][d4];
            qa[r] += dot4(xv, wq);
            ka[r] += dot4(xv, wk);
            va[r] += dot4(xv, wv);
        }
        #pragma unroll
        for (int rr = 0; rr < 4; ++rr) {
            const float4 xv = *(const float4*)&xs[rbase + rr][d4];
            qwe[rr] += dot4(xv, m2);
        }
    }
    #pragma unroll
    for (int r = 0; r < RPB; ++r) {
        Q [(size_t)(n0 + r) * HC + t] = qa[r];
        Kb[(size_t)(n0 + r) * HC + t] = f2bf(ka[r]);
        Vb[(size_t)(n0 + r) * HC + t] = f2bf(va[r]);
    }
    if (lane < 44) {
        #pragma unroll
        for (int rr = 0; rr < 4; ++rr)
            QWE[(size_t)(n0 + rbase + rr) * 44 + lane] = qwe[rr];
    }
}

// ---------------------------------------------------------------------------
// CSR build.
__global__ void zero_ints(int* __restrict__ a, int n) {
    const int i = blockIdx.x * blockDim.x + threadIdx.x;
    if (i < n) a[i] = 0;
}

__global__ void hist_deg(const int* __restrict__ dst, int* __restrict__ deg) {
    const int e = blockIdx.x * blockDim.x + threadIdx.x;
    if (e < N_EDGES) atomicAdd(&deg[dst[e]], 1);
}

__global__ void scan_local(const int* __restrict__ deg, int* __restrict__ rowstart,
                           int* __restrict__ psum) {
    __shared__ int s[256];
    const int b = blockIdx.x, t = threadIdx.x, i = b * 256 + t;
    const int v = (i < N_NODES) ? deg[i] : 0;
    s[t] = v;
    __syncthreads();
    for (int off = 1; off < 256; off <<= 1) {
        const int xr = (t >= off) ? s[t - off] : 0;
        __syncthreads();
        s[t] += xr;
        __syncthreads();
    }
    if (i < N_NODES) rowstart[i] = s[t] - v;  // exclusive within block
    if (t == 255) psum[b] = s[255];
}

// scan_add with fused psum prefix (each block scans the 196-entry psum in LDS)
__global__ void scan_add(int* __restrict__ rowstart, const int* __restrict__ psum) {
    __shared__ int s[256];
    __shared__ int ex[256];
    const int b = blockIdx.x, t = threadIdx.x;
    const int v = (t < NB_SCAN) ? psum[t] : 0;
    s[t] = v;
    __syncthreads();
    for (int off = 1; off < 256; off <<= 1) {
        const int xr = (t >= off) ? s[t - off] : 0;
        __syncthreads();
        s[t] += xr;
        __syncthreads();
    }
    ex[t] = s[t] - v;   // exclusive
    __syncthreads();
    const int i = b * 256 + t;
    if (i < N_NODES) rowstart[i] += ex[b];
}

__global__ void scatter_edges(const int* __restrict__ src, const int* __restrict__ dst,
                              const int* __restrict__ rowstart, int* __restrict__ cursor,
                              int2* __restrict__ ES) {
    const int e = blockIdx.x * blockDim.x + threadIdx.x;
    if (e >= N_EDGES) return;
    const int d = dst[e];
    const int pos = atomicAdd(&cursor[d], 1);
    ES[rowstart[d] + pos] = make_int2(e, src[e]);
}

// ---------------------------------------------------------------------------
// K2: fused attention, wave-parallel edges. Block = 256 = 1 dst node; wave w
// processes edges w, w+4, ... for ALL 256 channels (float4/lane). Per-wave
// online softmax state; final 4-way combine through LDS. No per-edge barriers.
__global__ void attn4(const float* __restrict__ ea,
                      const int2* __restrict__ ES,
                      const float* __restrict__ Q,
                      const float* __restrict__ QWE,
                      const ushort_t* __restrict__ Kb,
                      const ushort_t* __restrict__ Vb,
                      const int* __restrict__ rowstart,
                      const int* __restrict__ deg,
                      float* __restrict__ OUT,
                      float* __restrict__ TO) {
    __shared__ float CM[4][4];      // [wave][head] running max
    __shared__ float CD[4][4];      // [wave][head] denom
    __shared__ float4 CACC[4][64];  // [wave][lane] acc  (4 KB)
    __shared__ float CT[4][64];     // [wave][lane] T partial (j<11 valid)

    const int n = blockIdx.x;
    const int t = threadIdx.x;
    const int lane = t & 63;
    const int wid = t >> 6;
    const int h = lane >> 4;        // head of this lane's 16-group
    const int j = lane & 15;        // slot within group

    const float4 q4 = ((const float4*)Q)[(size_t)n * 64 + lane];
    const float qwe = (j < ED) ? QWE[(size_t)n * 44 + h * 11 + j] : 0.f;

    const int beg = __builtin_amdgcn_readfirstlane(rowstart[n]);
    const int dc  = __builtin_amdgcn_readfirstlane(deg[n]);

    float m = -INFINITY, den = 0.f, Tacc = 0.f;
    float4 acc = {0.f, 0.f, 0.f, 0.f};

    #pragma unroll 2
    for (int i = wid; i < dc; i += 4) {
        const int2 es = ES[beg + i];           // wave-uniform -> s_load_dwordx2
        const int e = es.x, s = es.y;
        const float eaj = (j < ED) ? ea[(size_t)e * ED + j] : 0.f;
        const ushort4 k4 = ((const ushort4*)(Kb + (size_t)s * HC))[lane];
        const ushort4 v4 = ((const ushort4*)(Vb + (size_t)s * HC))[lane];
        float p = q4.x * bf2f(k4.x) + q4.y * bf2f(k4.y)
                + q4.z * bf2f(k4.z) + q4.w * bf2f(k4.w)
                + eaj * qwe;
        p += __shfl_xor(p, 1, 64);
        p += __shfl_xor(p, 2, 64);
        p += __shfl_xor(p, 4, 64);
        p += __shfl_xor(p, 8, 64);
        const float alpha = p * 0.125f;        // /sqrt(64)
        const float mn = fmaxf(m, alpha);
        const float sc = __expf(m - mn);       // first edge: exp(-inf)=0
        const float ex = __expf(alpha - mn);
        acc.x = fmaf(ex, bf2f(v4.x), acc.x * sc);
        acc.y = fmaf(ex, bf2f(v4.y), acc.y * sc);
        acc.z = fmaf(ex, bf2f(v4.z), acc.z * sc);
        acc.w = fmaf(ex, bf2f(v4.w), acc.w * sc);
        den  = fmaf(den,  sc, ex);
        Tacc = fmaf(Tacc, sc, ex * eaj);
        m = mn;
    }

    if (j == 0) { CM[wid][h] = m; CD[wid][h] = den; }
    CACC[wid][lane] = acc;
    CT[wid][lane] = Tacc;
    __syncthreads();

    // combine: thread t owns output channel t (stored at wave lane t>>2, comp t&3)
    const int ls = t >> 2, kk = t & 3, hh = t >> 6;
    const float mstar = fmaxf(fmaxf(CM[0][hh], CM[1][hh]),
                              fmaxf(CM[2][hh], CM[3][hh]));
    float denf = 0.f, accf = 0.f;
    #pragma unroll
    for (int w = 0; w < 4; ++w) {
        const float mw = CM[w][hh];
        const float ewt = (mw > -INFINITY) ? __expf(mw - mstar) : 0.f;
        denf = fmaf(CD[w][hh], ewt, denf);
        const float* a = (const float*)&CACC[w][ls];
        accf = fmaf(a[kk], ewt, accf);
    }
    const float inv = (denf > 0.f) ? 1.f / denf : 0.f;
    OUT[(size_t)n * HC + t] = accf * inv;

    if (t < 64 && (t & 15) < ED) {
        const int h2 = t >> 4, j2 = t & 15;
        const float ms2 = fmaxf(fmaxf(CM[0][h2], CM[1][h2]),
                                fmaxf(CM[2][h2], CM[3][h2]));
        float dn2 = 0.f, tf = 0.f;
        #pragma unroll
        for (int w = 0; w < 4; ++w) {
            const float mw = CM[w][h2];
            const float ewt = (mw > -INFINITY) ? __expf(mw - ms2) : 0.f;
            dn2 = fmaf(CD[w][h2], ewt, dn2);
            tf  = fmaf(CT[w][t],  ewt, tf);
        }
        TO[(size_t)n * 44 + h2 * 11 + j2] = (dn2 > 0.f) ? tf / dn2 : 0.f;
    }
}

// ---------------------------------------------------------------------------
// K3: out = (OUT + TO@We + x@Wskip) @ Wlin. 16 nodes/block, float4 LDS reads.
__global__ void finalize16(const float* __restrict__ x,
                           const float* __restrict__ Wskip,
                           const float* __restrict__ Wlin,
                           const float* __restrict__ We,
                           const float* __restrict__ OUT,
                           const float* __restrict__ TO,
                           float* __restrict__ y) {
    __shared__ float sm[RPB][HC];    // 16 KB
    __shared__ float xs[RPB][DIN];   // 4 KB
    __shared__ float tos[RPB * 44];  // 2.8 KB
    const int n0 = blockIdx.x * RPB, t = threadIdx.x;
    const int h = t >> 6;
    #pragma unroll
    for (int i = 0; i < 4; ++i) {
        const int k = t * 4 + i;
        xs[k >> 6][k & 63] = x[n0 * DIN + k];
    }
    for (int i = t; i < RPB * 44; i += 256) tos[i] = TO[(size_t)n0 * 44 + i];
    __syncthreads();

    float w11[ED];
    #pragma unroll
    for (int jj = 0; jj < ED; ++jj) w11[jj] = We[jj * HC + t];

    float a[RPB];
    #pragma unroll
    for (int r = 0; r < RPB; ++r) {
        a[r] = OUT[(size_t)(n0 + r) * HC + t];
        #pragma unroll
        for (int jj = 0; jj < ED; ++jj)
            a[r] = fmaf(tos[r * 44 + h * 11 + jj], w11[jj], a[r]);
    }
    for (int d4 = 0; d4 < DIN; d4 += 4) {
        float4 w;
        w.x = Wskip[(d4 + 0) * HC + t]; w.y = Wskip[(d4 + 1) * HC + t];
        w.z = Wskip[(d4 + 2) * HC + t]; w.w = Wskip[(d4 + 3) * HC + t];
        #pragma unroll
        for (int r = 0; r < RPB; ++r) {
            const float4 xv = *(const float4*)&xs[r][d4];
            a[r] += dot4(xv, w);
        }
    }
    #pragma unroll
    for (int r = 0; r < RPB; ++r) sm[r][t] = a[r];
    __syncthreads();

    const int c = t & 63, r0 = (t >> 6) * 4;
    float b[4] = {0.f, 0.f, 0.f, 0.f};
    for (int j4 = 0; j4 < HC; j4 += 4) {
        float4 w;
        w.x = Wlin[(j4 + 0) * CPH + c]; w.y = Wlin[(j4 + 1) * CPH + c];
        w.z = Wlin[(j4 + 2) * CPH + c]; w.w = Wlin[(j4 + 3) * CPH + c];
        #pragma unroll
        for (int rr = 0; rr < 4; ++rr) {
            const float4 s4 = *(const float4*)&sm[r0 + rr][j4];
            b[rr] += dot4(s4, w);
        }
    }
    #pragma unroll
    for (int rr = 0; rr < 4; ++rr) y[(size_t)(n0 + r0 + rr) * CPH + c] = b[rr];
}

// ---------------------------------------------------------------------------
extern "C" void kernel_launch(void* const* d_in, const int* in_sizes, int n_in,
                              void* d_out, int out_size, void* d_ws, size_t ws_size,
                              hipStream_t stream) {
    const float* x     = (const float*)d_in[0];
    const float* ea    = (const float*)d_in[1];
    const int*   eidx  = (const int*)  d_in[2];
    const float* Wq    = (const float*)d_in[3];
    const float* Wk    = (const float*)d_in[4];
    const float* Wv    = (const float*)d_in[5];
    const float* We    = (const float*)d_in[6];
    const float* Wskip = (const float*)d_in[7];
    const float* Wlin  = (const float*)d_in[8];
    float* out = (float*)d_out;

    float* ws   = (float*)d_ws;
    float* Q    = ws;                           // N*256 f32
    float* OUT  = Q   + (size_t)N_NODES * HC;   // N*256 f32
    float* QWE  = OUT + (size_t)N_NODES * HC;   // N*44 f32
    float* TO   = QWE + (size_t)N_NODES * 44;   // N*44 f32
    float* M2   = TO  + (size_t)N_NODES * 44;   // 64*64 f32
    ushort_t* Kb = (ushort_t*)(M2 + 64 * 64);   // N*256 bf16
    ushort_t* Vb = Kb + (size_t)N_NODES * HC;   // N*256 bf16
    int* deg     = (int*)(Vb + (size_t)N_NODES * HC);
    int* rowstart= deg + NPAD;
    int* cursor  = rowstart + NPAD;
    int* psum    = cursor + NPAD;
    int2* ES     = (int2*)(psum + 256);         // E int2

    const int* src = eidx;
    const int* dst = eidx + N_EDGES;

    make_m2<<<16, 256, 0, stream>>>(Wq, We, M2);
    zero_ints<<<(3 * NPAD + 255) / 256, 256, 0, stream>>>(deg, 3 * NPAD);
    hist_deg<<<(N_EDGES + 255) / 256, 256, 0, stream>>>(dst, deg);
    scan_local<<<NB_SCAN, 256, 0, stream>>>(deg, rowstart, psum);
    scan_add<<<NB_SCAN, 256, 0, stream>>>(rowstart, psum);
    scatter_edges<<<(N_EDGES + 255) / 256, 256, 0, stream>>>(src, dst, rowstart, cursor, ES);

    node_proj<<<N_NODES / RPB, 256, 0, stream>>>(x, Wq, Wk, Wv, M2, Q, Kb, Vb, QWE);
    attn4<<<N_NODES, 256, 0, stream>>>(ea, ES, Q, QWE, Kb, Vb, rowstart, deg, OUT, TO);
    finalize16<<<N_NODES / RPB, 256, 0, stream>>>(x, Wskip, Wlin, We, OUT, TO, out);
}

// Round 6
// 469.776 us; speedup vs baseline: 3.7629x; 1.0162x over previous
//
#include <hip/hip_runtime.h>
#include <math.h>

#define N_NODES 50000
#define N_EDGES 800000
#define DIN 64
#define HC 256      // H*C
#define NH 4        // heads
#define CPH 64      // channels per head
#define ED 11
#define EAS 12      // EAp row stride
#define RPB 16      // rows per block in node_proj / finalize
#define NPAD 50176  // 196*256
#define NB_SCAN 196

typedef unsigned int uint;
typedef unsigned short ushort_t;

__device__ __forceinline__ ushort_t f2bf(float f) {
    uint u = __float_as_uint(f);
    u = (u + 0x7FFFu + ((u >> 16) & 1u)) >> 16;   // RTNE
    return (ushort_t)u;
}
__device__ __forceinline__ float bf2f(ushort_t h) {
    return __uint_as_float(((uint)h) << 16);
}
__device__ __forceinline__ float dot4(float4 a, float4 b) {
    return a.x * b.x + a.y * b.y + a.z * b.z + a.w * b.w;
}

// ---------------------------------------------------------------------------
// prep: M2[d][hj] = sum_c Wq[d,h*64+c]*We[j,h*64+c]  (first 4096 threads)
//       + zero deg/cursor (2*NPAD ints, following threads).
__global__ void prep(const float* __restrict__ Wq, const float* __restrict__ We,
                     float* __restrict__ M2, int* __restrict__ z) {
    const int g = blockIdx.x * 256 + threadIdx.x;
    if (g < 64 * 64) {
        const int d = g >> 6, hj = g & 63;
        float v = 0.f;
        if (hj < 44) {
            const int h = hj / 11, j = hj - h * 11;
            const float* wq = Wq + d * HC + h * 64;
            const float* we = We + j * HC + h * 64;
            #pragma unroll 8
            for (int c = 0; c < 64; ++c) v = fmaf(wq[c], we[c], v);
        }
        M2[g] = v;
    }
    const int zi = g - 64 * 64;
    if (zi >= 0 && zi < 2 * NPAD) z[zi] = 0;
}

// ---------------------------------------------------------------------------
// K1: Q (f32) + Kb,Vb (bf16) projections + QWE = x @ M2. 16 nodes/block.
__global__ void node_proj(const float* __restrict__ x,
                          const float* __restrict__ Wq,
                          const float* __restrict__ Wk,
                          const float* __restrict__ Wv,
                          const float* __restrict__ M2,
                          float* __restrict__ Q,
                          ushort_t* __restrict__ Kb,
                          ushort_t* __restrict__ Vb,
                          float* __restrict__ QWE) {
    __shared__ float xs[RPB][DIN];
    const int n0 = blockIdx.x * RPB;
    const int t = threadIdx.x;
    const int lane = t & 63, wid = t >> 6;
    const int rbase = wid * 4;
    #pragma unroll
    for (int i = 0; i < 4; ++i) {
        const int k = t * 4 + i;
        xs[k >> 6][k & 63] = x[n0 * DIN + k];
    }
    __syncthreads();

    float qa[RPB], ka[RPB], va[RPB];
    #pragma unroll
    for (int r = 0; r < RPB; ++r) { qa[r] = 0.f; ka[r] = 0.f; va[r] = 0.f; }
    float qwe[4] = {0.f, 0.f, 0.f, 0.f};

    for (int d4 = 0; d4 < DIN; d4 += 4) {
        float4 wq, wk, wv, m2;
        wq.x = Wq[(d4 + 0) * HC + t]; wq.y = Wq[(d4 + 1) * HC + t];
        wq.z = Wq[(d4 + 2) * HC + t]; wq.w = Wq[(d4 + 3) * HC + t];
        wk.x = Wk[(d4 + 0) * HC + t]; wk.y = Wk[(d4 + 1) * HC + t];
        wk.z = Wk[(d4 + 2) * HC + t]; wk.w = Wk[(d4 + 3) * HC + t];
        wv.x = Wv[(d4 + 0) * HC + t]; wv.y = Wv[(d4 + 1) * HC + t];
        wv.z = Wv[(d4 + 2) * HC + t]; wv.w = Wv[(d4 + 3) * HC + t];
        m2.x = M2[(d4 + 0) * 64 + lane]; m2.y = M2[(d4 + 1) * 64 + lane];
        m2.z = M2[(d4 + 2) * 64 + lane]; m2.w = M2[(d4 + 3) * 64 + lane];
        #pragma unroll
        for (int r = 0; r < RPB; ++r) {
            const float4 xv = *(const float4*)&xs[r][d4];
            qa[r] += dot4(xv, wq);
            ka[r] += dot4(xv, wk);
            va[r] += dot4(xv, wv);
        }
        #pragma unroll
        for (int rr = 0; rr < 4; ++rr) {
            const float4 xv = *(const float4*)&xs[rbase + rr][d4];
            qwe[rr] += dot4(xv, m2);
        }
    }
    #pragma unroll
    for (int r = 0; r < RPB; ++r) {
        Q [(size_t)(n0 + r) * HC + t] = qa[r];
        Kb[(size_t)(n0 + r) * HC + t] = f2bf(ka[r]);
        Vb[(size_t)(n0 + r) * HC + t] = f2bf(va[r]);
    }
    if (lane < 44) {
        #pragma unroll
        for (int rr = 0; rr < 4; ++rr)
            QWE[(size_t)(n0 + rbase + rr) * 44 + lane] = qwe[rr];
    }
}

// ---------------------------------------------------------------------------
// CSR build.
__global__ void hist_deg(const int* __restrict__ dst, int* __restrict__ deg) {
    const int e = blockIdx.x * blockDim.x + threadIdx.x;
    if (e < N_EDGES) atomicAdd(&deg[dst[e]], 1);
}

__global__ void scan_local(const int* __restrict__ deg, int* __restrict__ rowstart,
                           int* __restrict__ psum) {
    __shared__ int s[256];
    const int b = blockIdx.x, t = threadIdx.x, i = b * 256 + t;
    const int v = (i < N_NODES) ? deg[i] : 0;
    s[t] = v;
    __syncthreads();
    for (int off = 1; off < 256; off <<= 1) {
        const int xr = (t >= off) ? s[t - off] : 0;
        __syncthreads();
        s[t] += xr;
        __syncthreads();
    }
    if (i < N_NODES) rowstart[i] = s[t] - v;  // exclusive within block
    if (t == 255) psum[b] = s[255];
}

// scan_add with fused psum prefix (each block scans the 196-entry psum in LDS)
__global__ void scan_add(int* __restrict__ rowstart, const int* __restrict__ psum) {
    __shared__ int s[256];
    __shared__ int ex[256];
    const int b = blockIdx.x, t = threadIdx.x;
    const int v = (t < NB_SCAN) ? psum[t] : 0;
    s[t] = v;
    __syncthreads();
    for (int off = 1; off < 256; off <<= 1) {
        const int xr = (t >= off) ? s[t - off] : 0;
        __syncthreads();
        s[t] += xr;
        __syncthreads();
    }
    ex[t] = s[t] - v;   // exclusive
    __syncthreads();
    const int i = b * 256 + t;
    if (i < N_NODES) rowstart[i] += ex[b];
}

// scatter: permute src and edge features into CSR (dst-sorted) order.
__global__ void scatter_edges(const int* __restrict__ src, const int* __restrict__ dst,
                              const float* __restrict__ ea,
                              const int* __restrict__ rowstart, int* __restrict__ cursor,
                              int* __restrict__ SRCp, float* __restrict__ EAp) {
    const int e = blockIdx.x * blockDim.x + threadIdx.x;
    if (e >= N_EDGES) return;
    const int d = dst[e];
    const int pos = atomicAdd(&cursor[d], 1);
    const int idx = rowstart[d] + pos;
    SRCp[idx] = src[e];
    float* o = EAp + (size_t)idx * EAS;
    const float* in = ea + (size_t)e * ED;
    #pragma unroll
    for (int j = 0; j < ED; ++j) o[j] = in[j];
}

// ---------------------------------------------------------------------------
// K2: fused attention, 1 wave = 1 dst node (4 nodes / 256-block). No LDS, no
// barriers. Unroll-2 pairwise online softmax; EAp/SRCp sequential in CSR order.
__global__ void attn5(const float* __restrict__ EAp,
                      const int* __restrict__ SRCp,
                      const float* __restrict__ Q,
                      const float* __restrict__ QWE,
                      const ushort_t* __restrict__ Kb,
                      const ushort_t* __restrict__ Vb,
                      const int* __restrict__ rowstart,
                      const int* __restrict__ deg,
                      float* __restrict__ OUT,
                      float* __restrict__ TO) {
    const int t = threadIdx.x;
    const int lane = t & 63;
    const int wid = t >> 6;
    const int n = blockIdx.x * 4 + wid;   // N_NODES % 4 == 0
    const int h = lane >> 4;              // head
    const int j = lane & 15;              // slot within head

    const float4 q4 = ((const float4*)Q)[(size_t)n * 64 + lane];
    const float qwe = (j < ED) ? QWE[(size_t)n * 44 + h * 11 + j] : 0.f;

    const int beg = __builtin_amdgcn_readfirstlane(rowstart[n]);
    const int dc  = __builtin_amdgcn_readfirstlane(deg[n]);

    float m = -INFINITY, den = 0.f, Tacc = 0.f;
    float4 acc = {0.f, 0.f, 0.f, 0.f};

    int i = 0;
    for (; i + 2 <= dc; i += 2) {
        const int i0 = beg + i, i1 = i0 + 1;
        const int s0 = SRCp[i0];              // uniform -> s_load
        const int s1 = SRCp[i1];
        const float ea0 = (j < ED) ? EAp[(size_t)i0 * EAS + j] : 0.f;
        const float ea1 = (j < ED) ? EAp[(size_t)i1 * EAS + j] : 0.f;
        const ushort4 k0 = ((const ushort4*)(Kb + (size_t)s0 * HC))[lane];
        const ushort4 k1 = ((const ushort4*)(Kb + (size_t)s1 * HC))[lane];
        const ushort4 v0 = ((const ushort4*)(Vb + (size_t)s0 * HC))[lane];
        const ushort4 v1 = ((const ushort4*)(Vb + (size_t)s1 * HC))[lane];

        float p0 = q4.x * bf2f(k0.x) + q4.y * bf2f(k0.y)
                 + q4.z * bf2f(k0.z) + q4.w * bf2f(k0.w) + ea0 * qwe;
        float p1 = q4.x * bf2f(k1.x) + q4.y * bf2f(k1.y)
                 + q4.z * bf2f(k1.z) + q4.w * bf2f(k1.w) + ea1 * qwe;
        p0 += __shfl_xor(p0, 1, 64);  p1 += __shfl_xor(p1, 1, 64);
        p0 += __shfl_xor(p0, 2, 64);  p1 += __shfl_xor(p1, 2, 64);
        p0 += __shfl_xor(p0, 4, 64);  p1 += __shfl_xor(p1, 4, 64);
        p0 += __shfl_xor(p0, 8, 64);  p1 += __shfl_xor(p1, 8, 64);
        const float a0 = p0 * 0.125f, a1 = p1 * 0.125f;

        const float M = fmaxf(fmaxf(m, a0), a1);
        const float sc = __expf(m - M);       // first pair: exp(-inf)=0
        const float e0 = __expf(a0 - M);
        const float e1 = __expf(a1 - M);
        acc.x = fmaf(e0, bf2f(v0.x), fmaf(e1, bf2f(v1.x), acc.x * sc));
        acc.y = fmaf(e0, bf2f(v0.y), fmaf(e1, bf2f(v1.y), acc.y * sc));
        acc.z = fmaf(e0, bf2f(v0.z), fmaf(e1, bf2f(v1.z), acc.z * sc));
        acc.w = fmaf(e0, bf2f(v0.w), fmaf(e1, bf2f(v1.w), acc.w * sc));
        den  = fmaf(den, sc, e0 + e1);
        Tacc = fmaf(Tacc, sc, fmaf(e0, ea0, e1 * ea1));
        m = M;
    }
    if (i < dc) {                              // odd tail
        const int i0 = beg + i;
        const int s0 = SRCp[i0];
        const float ea0 = (j < ED) ? EAp[(size_t)i0 * EAS + j] : 0.f;
        const ushort4 k0 = ((const ushort4*)(Kb + (size_t)s0 * HC))[lane];
        const ushort4 v0 = ((const ushort4*)(Vb + (size_t)s0 * HC))[lane];
        float p0 = q4.x * bf2f(k0.x) + q4.y * bf2f(k0.y)
                 + q4.z * bf2f(k0.z) + q4.w * bf2f(k0.w) + ea0 * qwe;
        p0 += __shfl_xor(p0, 1, 64);
        p0 += __shfl_xor(p0, 2, 64);
        p0 += __shfl_xor(p0, 4, 64);
        p0 += __shfl_xor(p0, 8, 64);
        const float a0 = p0 * 0.125f;
        const float M = fmaxf(m, a0);
        const float sc = __expf(m - M);
        const float e0 = __expf(a0 - M);
        acc.x = fmaf(e0, bf2f(v0.x), acc.x * sc);
        acc.y = fmaf(e0, bf2f(v0.y), acc.y * sc);
        acc.z = fmaf(e0, bf2f(v0.z), acc.z * sc);
        acc.w = fmaf(e0, bf2f(v0.w), acc.w * sc);
        den  = fmaf(den, sc, e0);
        Tacc = fmaf(Tacc, sc, e0 * ea0);
    }

    const float inv = (den > 0.f) ? 1.f / den : 0.f;
    float4 o;
    o.x = acc.x * inv; o.y = acc.y * inv; o.z = acc.z * inv; o.w = acc.w * inv;
    ((float4*)OUT)[(size_t)n * 64 + lane] = o;
    if (j < ED) TO[(size_t)n * 44 + h * 11 + j] = Tacc * inv;
}

// ---------------------------------------------------------------------------
// K3: out = (OUT + TO@We + x@Wskip) @ Wlin. 16 nodes/block, float4 LDS reads.
__global__ void finalize16(const float* __restrict__ x,
                           const float* __restrict__ Wskip,
                           const float* __restrict__ Wlin,
                           const float* __restrict__ We,
                           const float* __restrict__ OUT,
                           const float* __restrict__ TO,
                           float* __restrict__ y) {
    __shared__ float sm[RPB][HC];    // 16 KB
    __shared__ float xs[RPB][DIN];   // 4 KB
    __shared__ float tos[RPB * 44];  // 2.8 KB
    const int n0 = blockIdx.x * RPB, t = threadIdx.x;
    const int h = t >> 6;
    #pragma unroll
    for (int i = 0; i < 4; ++i) {
        const int k = t * 4 + i;
        xs[k >> 6][k & 63] = x[n0 * DIN + k];
    }
    for (int i = t; i < RPB * 44; i += 256) tos[i] = TO[(size_t)n0 * 44 + i];
    __syncthreads();

    float w11[ED];
    #pragma unroll
    for (int jj = 0; jj < ED; ++jj) w11[jj] = We[jj * HC + t];

    float a[RPB];
    #pragma unroll
    for (int r = 0; r < RPB; ++r) {
        a[r] = OUT[(size_t)(n0 + r) * HC + t];
        #pragma unroll
        for (int jj = 0; jj < ED; ++jj)
            a[r] = fmaf(tos[r * 44 + h * 11 + jj], w11[jj], a[r]);
    }
    for (int d4 = 0; d4 < DIN; d4 += 4) {
        float4 w;
        w.x = Wskip[(d4 + 0) * HC + t]; w.y = Wskip[(d4 + 1) * HC + t];
        w.z = Wskip[(d4 + 2) * HC + t]; w.w = Wskip[(d4 + 3) * HC + t];
        #pragma unroll
        for (int r = 0; r < RPB; ++r) {
            const float4 xv = *(const float4*)&xs[r][d4];
            a[r] += dot4(xv, w);
        }
    }
    #pragma unroll
    for (int r = 0; r < RPB; ++r) sm[r][t] = a[r];
    __syncthreads();

    const int c = t & 63, r0 = (t >> 6) * 4;
    float b[4] = {0.f, 0.f, 0.f, 0.f};
    for (int j4 = 0; j4 < HC; j4 += 4) {
        float4 w;
        w.x = Wlin[(j4 + 0) * CPH + c]; w.y = Wlin[(j4 + 1) * CPH + c];
        w.z = Wlin[(j4 + 2) * CPH + c]; w.w = Wlin[(j4 + 3) * CPH + c];
        #pragma unroll
        for (int rr = 0; rr < 4; ++rr) {
            const float4 s4 = *(const float4*)&sm[r0 + rr][j4];
            b[rr] += dot4(s4, w);
        }
    }
    #pragma unroll
    for (int rr = 0; rr < 4; ++rr) y[(size_t)(n0 + r0 + rr) * CPH + c] = b[rr];
}

// ---------------------------------------------------------------------------
extern "C" void kernel_launch(void* const* d_in, const int* in_sizes, int n_in,
                              void* d_out, int out_size, void* d_ws, size_t ws_size,
                              hipStream_t stream) {
    const float* x     = (const float*)d_in[0];
    const float* ea    = (const float*)d_in[1];
    const int*   eidx  = (const int*)  d_in[2];
    const float* Wq    = (const float*)d_in[3];
    const float* Wk    = (const float*)d_in[4];
    const float* Wv    = (const float*)d_in[5];
    const float* We    = (const float*)d_in[6];
    const float* Wskip = (const float*)d_in[7];
    const float* Wlin  = (const float*)d_in[8];
    float* out = (float*)d_out;

    float* ws   = (float*)d_ws;
    float* Q    = ws;                           // N*256 f32
    float* OUT  = Q   + (size_t)N_NODES * HC;   // N*256 f32
    float* QWE  = OUT + (size_t)N_NODES * HC;   // N*44 f32
    float* TO   = QWE + (size_t)N_NODES * 44;   // N*44 f32
    float* M2   = TO  + (size_t)N_NODES * 44;   // 64*64 f32
    ushort_t* Kb = (ushort_t*)(M2 + 64 * 64);   // N*256 bf16
    ushort_t* Vb = Kb + (size_t)N_NODES * HC;   // N*256 bf16
    int* deg     = (int*)(Vb + (size_t)N_NODES * HC);  // NPAD
    int* cursor  = deg + NPAD;                  // NPAD (adjacent to deg: zeroed together)
    int* rowstart= cursor + NPAD;               // NPAD
    int* psum    = rowstart + NPAD;             // 256
    int* SRCp    = psum + 256;                  // E
    float* EAp   = (float*)(SRCp + N_EDGES);    // E*12 f32

    const int* src = eidx;
    const int* dst = eidx + N_EDGES;

    prep<<<(64 * 64 + 2 * NPAD + 255) / 256, 256, 0, stream>>>(Wq, We, M2, deg);
    hist_deg<<<(N_EDGES + 255) / 256, 256, 0, stream>>>(dst, deg);
    scan_local<<<NB_SCAN, 256, 0, stream>>>(deg, rowstart, psum);
    scan_add<<<NB_SCAN, 256, 0, stream>>>(rowstart, psum);
    scatter_edges<<<(N_EDGES + 255) / 256, 256, 0, stream>>>(src, dst, ea, rowstart,
                                                             cursor, SRCp, EAp);

    node_proj<<<N_NODES / RPB, 256, 0, stream>>>(x, Wq, Wk, Wv, M2, Q, Kb, Vb, QWE);
    attn5<<<N_NODES / 4, 256, 0, stream>>>(EAp, SRCp, Q, QWE, Kb, Vb,
                                           rowstart, deg, OUT, TO);
    finalize16<<<N_NODES / RPB, 256, 0, stream>>>(x, Wskip, Wlin, We, OUT, TO, out);
}

// Round 8
// 450.390 us; speedup vs baseline: 3.9248x; 1.0430x over previous
//
#include <hip/hip_runtime.h>
#include <math.h>

#define N_NODES 50000
#define N_EDGES 800000
#define DIN 64
#define HC 256      // H*C
#define NH 4        // heads
#define CPH 64      // channels per head
#define ED 11
#define RPB 16      // rows per block in node_proj / finalize
#define NPAD 50176  // 196*256
#define NB_SCAN 196

typedef unsigned int uint;
typedef unsigned short ushort_t;

__device__ __forceinline__ ushort_t f2bf(float f) {
    uint u = __float_as_uint(f);
    u = (u + 0x7FFFu + ((u >> 16) & 1u)) >> 16;   // RTNE
    return (ushort_t)u;
}
__device__ __forceinline__ float bf2f(ushort_t h) {
    return __uint_as_float(((uint)h) << 16);
}
__device__ __forceinline__ float dot4(float4 a, float4 b) {
    return a.x * b.x + a.y * b.y + a.z * b.z + a.w * b.w;
}

// ---------------------------------------------------------------------------
// prep: G[d][h*64+dp] = sum_c Wq[d,h*64+c]*Wk[dp,h*64+c]   (G_h = Wq_h·Wk_hᵀ)
//       M2[d][h*11+j] = sum_c Wq[d,h*64+c]*We[j,h*64+c]
//       zero deg/cursor (2*NPAD ints).
__global__ void prep(const float* __restrict__ Wq, const float* __restrict__ Wk,
                     const float* __restrict__ We,
                     float* __restrict__ G, float* __restrict__ M2,
                     int* __restrict__ z) {
    const int g = blockIdx.x * 256 + threadIdx.x;
    if (g < 64 * HC) {
        const int d = g >> 8, hc = g & 255;
        const int hb = hc & 192, dp = hc & 63;   // head base, second input dim
        const float* bq = Wq + d * HC + hb;      // Wq[d, hb..hb+63]
        const float* bk = Wk + dp * HC + hb;     // Wk[dp, hb..hb+63]
        float v = 0.f;
        #pragma unroll 8
        for (int c = 0; c < 64; ++c) v = fmaf(bq[c], bk[c], v);
        G[g] = v;
    } else if (g < 64 * HC + 64 * 64) {
        const int gm = g - 64 * HC;
        const int d = gm >> 6, hj = gm & 63;
        float v = 0.f;
        if (hj < 44) {
            const int h = hj / 11, j = hj - h * 11;
            const float* wq = Wq + d * HC + h * 64;
            const float* we = We + j * HC + h * 64;
            #pragma unroll 8
            for (int c = 0; c < 64; ++c) v = fmaf(wq[c], we[c], v);
        }
        M2[gm] = v;
    } else {
        const int zi = g - (64 * HC + 64 * 64);
        if (zi < 2 * NPAD) z[zi] = 0;
    }
}

// ---------------------------------------------------------------------------
// K1: P = x@G (f32), QWE = x@M2, xb = bf16(x). 16 nodes/block.
__global__ void node_proj2(const float* __restrict__ x,
                           const float* __restrict__ G,
                           const float* __restrict__ M2,
                           float* __restrict__ P,
                           float* __restrict__ QWE,
                           ushort_t* __restrict__ xb) {
    __shared__ float xs[RPB][DIN];
    const int n0 = blockIdx.x * RPB;
    const int t = threadIdx.x;
    const int lane = t & 63, wid = t >> 6;
    const int rbase = wid * 4;
    {
        const float4 xv4 = ((const float4*)x)[(size_t)n0 * 16 + t];
        const int k = t * 4;
        *(float4*)&xs[k >> 6][k & 63] = xv4;
        ushort4 b;
        b.x = f2bf(xv4.x); b.y = f2bf(xv4.y); b.z = f2bf(xv4.z); b.w = f2bf(xv4.w);
        ((ushort4*)xb)[(size_t)n0 * 16 + t] = b;
    }
    __syncthreads();

    float pa[RPB];
    #pragma unroll
    for (int r = 0; r < RPB; ++r) pa[r] = 0.f;
    float qwe[4] = {0.f, 0.f, 0.f, 0.f};

    for (int d4 = 0; d4 < DIN; d4 += 4) {
        float4 wg, m2;
        wg.x = G[(d4 + 0) * HC + t]; wg.y = G[(d4 + 1) * HC + t];
        wg.z = G[(d4 + 2) * HC + t]; wg.w = G[(d4 + 3) * HC + t];
        m2.x = M2[(d4 + 0) * 64 + lane]; m2.y = M2[(d4 + 1) * 64 + lane];
        m2.z = M2[(d4 + 2) * 64 + lane]; m2.w = M2[(d4 + 3) * 64 + lane];
        #pragma unroll
        for (int r = 0; r < RPB; ++r) {
            const float4 xv = *(const float4*)&xs[r][d4];
            pa[r] += dot4(xv, wg);
        }
        #pragma unroll
        for (int rr = 0; rr < 4; ++rr) {
            const float4 xv = *(const float4*)&xs[rbase + rr][d4];
            qwe[rr] += dot4(xv, m2);
        }
    }
    #pragma unroll
    for (int r = 0; r < RPB; ++r) P[(size_t)(n0 + r) * HC + t] = pa[r];
    if (lane < 44) {
        #pragma unroll
        for (int rr = 0; rr < 4; ++rr)
            QWE[(size_t)(n0 + rbase + rr) * 44 + lane] = qwe[rr];
    }
}

// ---------------------------------------------------------------------------
// CSR build.
__global__ void hist_deg(const int* __restrict__ dst, int* __restrict__ deg) {
    const int e = blockIdx.x * blockDim.x + threadIdx.x;
    if (e < N_EDGES) atomicAdd(&deg[dst[e]], 1);
}

__global__ void scan_local(const int* __restrict__ deg, int* __restrict__ rowstart,
                           int* __restrict__ psum) {
    __shared__ int s[256];
    const int b = blockIdx.x, t = threadIdx.x, i = b * 256 + t;
    const int v = (i < N_NODES) ? deg[i] : 0;
    s[t] = v;
    __syncthreads();
    for (int off = 1; off < 256; off <<= 1) {
        const int xr = (t >= off) ? s[t - off] : 0;
        __syncthreads();
        s[t] += xr;
        __syncthreads();
    }
    if (i < N_NODES) rowstart[i] = s[t] - v;  // exclusive within block
    if (t == 255) psum[b] = s[255];
}

__global__ void scan_add(int* __restrict__ rowstart, const int* __restrict__ psum) {
    __shared__ int s[256];
    __shared__ int ex[256];
    const int b = blockIdx.x, t = threadIdx.x;
    const int v = (t < NB_SCAN) ? psum[t] : 0;
    s[t] = v;
    __syncthreads();
    for (int off = 1; off < 256; off <<= 1) {
        const int xr = (t >= off) ? s[t - off] : 0;
        __syncthreads();
        s[t] += xr;
        __syncthreads();
    }
    ex[t] = s[t] - v;   // exclusive
    __syncthreads();
    const int i = b * 256 + t;
    if (i < N_NODES) rowstart[i] += ex[b];
}

// scatter: build 32B per-edge records in CSR (dst-sorted) order:
// ushort bf16 ea[11], pad, int src, pad.
__global__ void scatter_edges2(const int* __restrict__ src, const int* __restrict__ dst,
                               const float* __restrict__ ea,
                               const int* __restrict__ rowstart, int* __restrict__ cursor,
                               uint* __restrict__ EREC) {
    const int e = blockIdx.x * blockDim.x + threadIdx.x;
    if (e >= N_EDGES) return;
    const int d = dst[e];
    const int pos = atomicAdd(&cursor[d], 1);
    const size_t idx = (size_t)rowstart[d] + pos;
    const float* in = ea + (size_t)e * ED;
    uint w[8];
    #pragma unroll
    for (int jj = 0; jj < 5; ++jj)
        w[jj] = (uint)f2bf(in[2 * jj]) | ((uint)f2bf(in[2 * jj + 1]) << 16);
    w[5] = (uint)f2bf(in[10]);
    w[6] = (uint)src[e];
    w[7] = 0u;
    uint4* o = (uint4*)(EREC + idx * 8);
    o[0] = make_uint4(w[0], w[1], w[2], w[3]);
    o[1] = make_uint4(w[4], w[5], w[6], w[7]);
}

// ---------------------------------------------------------------------------
// K2: fused attention on RAW x gathers (bf16, 128B/edge from a 6.4MB table).
// 1 wave = 1 dst node. alpha = P[n,h]·x_j + ea·QWE; xagg += ex*x_j.
__global__ void attn6(const uint* __restrict__ EREC,
                      const float* __restrict__ P,
                      const float* __restrict__ QWE,
                      const ushort_t* __restrict__ xb,
                      const int* __restrict__ rowstart,
                      const int* __restrict__ deg,
                      float* __restrict__ OUT,
                      float* __restrict__ TO) {
    const int t = threadIdx.x;
    const int lane = t & 63;
    const int wid = t >> 6;
    const int n = blockIdx.x * 4 + wid;   // N_NODES % 4 == 0
    const int h = lane >> 4;              // head
    const int j = lane & 15;              // slot: channels 4j..4j+3 of this head

    const float4 p4 = ((const float4*)P)[(size_t)n * 64 + lane];
    const float qwe = (j < ED) ? QWE[(size_t)n * 44 + h * 11 + j] : 0.f;

    const int beg = __builtin_amdgcn_readfirstlane(rowstart[n]);
    const int dc  = __builtin_amdgcn_readfirstlane(deg[n]);

    float m = -INFINITY, den = 0.f, Tacc = 0.f;
    float4 acc = {0.f, 0.f, 0.f, 0.f};

    int i = 0;
    for (; i + 2 <= dc; i += 2) {
        const ushort_t* r0 = (const ushort_t*)(EREC + (size_t)(beg + i) * 8);
        const ushort_t* r1 = r0 + 16;
        const int s0 = __builtin_amdgcn_readfirstlane(((const int*)r0)[6]);
        const int s1 = __builtin_amdgcn_readfirstlane(((const int*)r1)[6]);
        const float ea0 = (j < ED) ? bf2f(r0[j]) : 0.f;
        const float ea1 = (j < ED) ? bf2f(r1[j]) : 0.f;
        const ushort4 x0 = ((const ushort4*)(xb + (size_t)s0 * DIN))[j];
        const ushort4 x1 = ((const ushort4*)(xb + (size_t)s1 * DIN))[j];

        float p0 = p4.x * bf2f(x0.x) + p4.y * bf2f(x0.y)
                 + p4.z * bf2f(x0.z) + p4.w * bf2f(x0.w) + ea0 * qwe;
        float p1 = p4.x * bf2f(x1.x) + p4.y * bf2f(x1.y)
                 + p4.z * bf2f(x1.z) + p4.w * bf2f(x1.w) + ea1 * qwe;
        p0 += __shfl_xor(p0, 1, 64);  p1 += __shfl_xor(p1, 1, 64);
        p0 += __shfl_xor(p0, 2, 64);  p1 += __shfl_xor(p1, 2, 64);
        p0 += __shfl_xor(p0, 4, 64);  p1 += __shfl_xor(p1, 4, 64);
        p0 += __shfl_xor(p0, 8, 64);  p1 += __shfl_xor(p1, 8, 64);
        const float a0 = p0 * 0.125f, a1 = p1 * 0.125f;

        const float M = fmaxf(fmaxf(m, a0), a1);
        const float sc = __expf(m - M);       // first pair: exp(-inf)=0
        const float e0 = __expf(a0 - M);
        const float e1 = __expf(a1 - M);
        acc.x = fmaf(e0, bf2f(x0.x), fmaf(e1, bf2f(x1.x), acc.x * sc));
        acc.y = fmaf(e0, bf2f(x0.y), fmaf(e1, bf2f(x1.y), acc.y * sc));
        acc.z = fmaf(e0, bf2f(x0.z), fmaf(e1, bf2f(x1.z), acc.z * sc));
        acc.w = fmaf(e0, bf2f(x0.w), fmaf(e1, bf2f(x1.w), acc.w * sc));
        den  = fmaf(den, sc, e0 + e1);
        Tacc = fmaf(Tacc, sc, fmaf(e0, ea0, e1 * ea1));
        m = M;
    }
    if (i < dc) {                              // odd tail
        const ushort_t* r0 = (const ushort_t*)(EREC + (size_t)(beg + i) * 8);
        const int s0 = __builtin_amdgcn_readfirstlane(((const int*)r0)[6]);
        const float ea0 = (j < ED) ? bf2f(r0[j]) : 0.f;
        const ushort4 x0 = ((const ushort4*)(xb + (size_t)s0 * DIN))[j];
        float p0 = p4.x * bf2f(x0.x) + p4.y * bf2f(x0.y)
                 + p4.z * bf2f(x0.z) + p4.w * bf2f(x0.w) + ea0 * qwe;
        p0 += __shfl_xor(p0, 1, 64);
        p0 += __shfl_xor(p0, 2, 64);
        p0 += __shfl_xor(p0, 4, 64);
        p0 += __shfl_xor(p0, 8, 64);
        const float a0 = p0 * 0.125f;
        const float M = fmaxf(m, a0);
        const float sc = __expf(m - M);
        const float e0 = __expf(a0 - M);
        acc.x = fmaf(e0, bf2f(x0.x), acc.x * sc);
        acc.y = fmaf(e0, bf2f(x0.y), acc.y * sc);
        acc.z = fmaf(e0, bf2f(x0.z), acc.z * sc);
        acc.w = fmaf(e0, bf2f(x0.w), acc.w * sc);
        den  = fmaf(den, sc, e0);
        Tacc = fmaf(Tacc, sc, e0 * ea0);
    }

    const float inv = (den > 0.f) ? 1.f / den : 0.f;
    float4 o;
    o.x = acc.x * inv; o.y = acc.y * inv; o.z = acc.z * inv; o.w = acc.w * inv;
    ((float4*)OUT)[(size_t)n * 64 + lane] = o;   // xagg[n][h*64 + 4j..]
    if (j < ED) TO[(size_t)n * 44 + h * 11 + j] = Tacc * inv;
}

// ---------------------------------------------------------------------------
// K3: y = (xagg@Wv + TO@We + x@Wskip) @ Wlin. 16 nodes/block.
// xg LDS buffer is reused as sm in phase 2 (union in time).
__global__ void finalize17(const float* __restrict__ x,
                           const float* __restrict__ Wv,
                           const float* __restrict__ Wskip,
                           const float* __restrict__ Wlin,
                           const float* __restrict__ We,
                           const float* __restrict__ OUT,
                           const float* __restrict__ TO,
                           float* __restrict__ y) {
    __shared__ float xg[RPB][HC];    // 16 KB: phase1 xagg rows, phase2 sm
    __shared__ float xs[RPB][DIN];   // 4 KB
    __shared__ float tos[RPB * 44];  // 2.8 KB
    const int n0 = blockIdx.x * RPB, t = threadIdx.x;
    const int h = t >> 6;
    const int hb = h * 64;
    {
        const float4 xv4 = ((const float4*)x)[(size_t)n0 * 16 + t];
        const int k = t * 4;
        *(float4*)&xs[k >> 6][k & 63] = xv4;
    }
    #pragma unroll
    for (int r = 0; r < RPB; ++r) xg[r][t] = OUT[(size_t)(n0 + r) * HC + t];
    for (int i2 = t; i2 < RPB * 44; i2 += 256) tos[i2] = TO[(size_t)n0 * 44 + i2];
    __syncthreads();

    float w11[ED];
    #pragma unroll
    for (int jj = 0; jj < ED; ++jj) w11[jj] = We[jj * HC + t];

    float a[RPB];
    #pragma unroll
    for (int r = 0; r < RPB; ++r) {
        float v = 0.f;
        #pragma unroll
        for (int jj = 0; jj < ED; ++jj)
            v = fmaf(tos[r * 44 + h * 11 + jj], w11[jj], v);
        a[r] = v;
    }
    for (int d4 = 0; d4 < DIN; d4 += 4) {
        float4 wv4, ws4;
        wv4.x = Wv[(d4 + 0) * HC + t]; wv4.y = Wv[(d4 + 1) * HC + t];
        wv4.z = Wv[(d4 + 2) * HC + t]; wv4.w = Wv[(d4 + 3) * HC + t];
        ws4.x = Wskip[(d4 + 0) * HC + t]; ws4.y = Wskip[(d4 + 1) * HC + t];
        ws4.z = Wskip[(d4 + 2) * HC + t]; ws4.w = Wskip[(d4 + 3) * HC + t];
        #pragma unroll
        for (int r = 0; r < RPB; ++r) {
            const float4 xv = *(const float4*)&xs[r][d4];
            const float4 gg = *(const float4*)&xg[r][hb + d4];
            a[r] += dot4(xv, ws4) + dot4(gg, wv4);
        }
    }
    __syncthreads();
    #pragma unroll
    for (int r = 0; r < RPB; ++r) xg[r][t] = a[r];   // sm
    __syncthreads();

    const int c = t & 63, r0 = (t >> 6) * 4;
    float b[4] = {0.f, 0.f, 0.f, 0.f};
    for (int j4 = 0; j4 < HC; j4 += 4) {
        float4 w;
        w.x = Wlin[(j4 + 0) * CPH + c]; w.y = Wlin[(j4 + 1) * CPH + c];
        w.z = Wlin[(j4 + 2) * CPH + c]; w.w = Wlin[(j4 + 3) * CPH + c];
        #pragma unroll
        for (int rr = 0; rr < 4; ++rr) {
            const float4 s4 = *(const float4*)&xg[r0 + rr][j4];
            b[rr] += dot4(s4, w);
        }
    }
    #pragma unroll
    for (int rr = 0; rr < 4; ++rr) y[(size_t)(n0 + r0 + rr) * CPH + c] = b[rr];
}

// ---------------------------------------------------------------------------
extern "C" void kernel_launch(void* const* d_in, const int* in_sizes, int n_in,
                              void* d_out, int out_size, void* d_ws, size_t ws_size,
                              hipStream_t stream) {
    const float* x     = (const float*)d_in[0];
    const float* ea    = (const float*)d_in[1];
    const int*   eidx  = (const int*)  d_in[2];
    const float* Wq    = (const float*)d_in[3];
    const float* Wk    = (const float*)d_in[4];
    const float* Wv    = (const float*)d_in[5];
    const float* We    = (const float*)d_in[6];
    const float* Wskip = (const float*)d_in[7];
    const float* Wlin  = (const float*)d_in[8];
    float* out = (float*)d_out;

    float* ws   = (float*)d_ws;
    float* P    = ws;                           // N*256 f32
    float* OUT  = P   + (size_t)N_NODES * HC;   // N*256 f32 (xagg)
    float* QWE  = OUT + (size_t)N_NODES * HC;   // N*44 f32
    float* TO   = QWE + (size_t)N_NODES * 44;   // N*44 f32
    float* M2   = TO  + (size_t)N_NODES * 44;   // 64*64 f32
    float* G    = M2  + 64 * 64;                // 64*256 f32
    int* deg     = (int*)(G + 64 * HC);         // NPAD
    int* cursor  = deg + NPAD;                  // NPAD (zeroed with deg)
    int* rowstart= cursor + NPAD;               // NPAD
    int* psum    = rowstart + NPAD;             // 256
    ushort_t* xb = (ushort_t*)(psum + 256);     // N*64 bf16
    uint* EREC   = (uint*)(xb + (size_t)N_NODES * DIN);  // E*32B (32B-aligned)

    const int* src = eidx;
    const int* dst = eidx + N_EDGES;

    prep<<<(64 * HC + 64 * 64 + 2 * NPAD + 255) / 256, 256, 0, stream>>>(
        Wq, Wk, We, G, M2, deg);
    hist_deg<<<(N_EDGES + 255) / 256, 256, 0, stream>>>(dst, deg);
    scan_local<<<NB_SCAN, 256, 0, stream>>>(deg, rowstart, psum);
    scan_add<<<NB_SCAN, 256, 0, stream>>>(rowstart, psum);
    scatter_edges2<<<(N_EDGES + 255) / 256, 256, 0, stream>>>(src, dst, ea, rowstart,
                                                              cursor, EREC);

    node_proj2<<<N_NODES / RPB, 256, 0, stream>>>(x, G, M2, P, QWE, xb);
    attn6<<<N_NODES / 4, 256, 0, stream>>>(EREC, P, QWE, xb, rowstart, deg, OUT, TO);
    finalize17<<<N_NODES / RPB, 256, 0, stream>>>(x, Wv, Wskip, Wlin, We, OUT, TO, out);
}